// Round 5
// baseline (588.422 us; speedup 1.0000x reference)
//
#include <hip/hip_runtime.h>
#include <stdint.h>

// Problem constants
#define T_ 4
#define B_ 16
#define N_ 197
#define D_ 512
#define H_ 8
#define DH 64
#define BN_ (B_*N_)              // 3152 rows per timestep
#define PLANE (BN_*D_)           // 1,613,824 elems per t-plane
#define M_ (T_*BN_)              // 12608 GEMM rows
#define TENSOR_ELEMS (T_*PLANE)  // 6,455,296 elems per (T,B,N,D) tensor
#define WELEMS (D_*D_)           // 262,144
#define MH (M_*H_)               // 100,864 bitmask words per tensor
#define FLAG_TOL 6e-3f           // ~13 sigma of single-pass f16 dot error
#define MAXFLAG 262144

typedef __attribute__((ext_vector_type(8))) short short8v;
typedef __attribute__((ext_vector_type(8))) _Float16 f16x8;
typedef __attribute__((ext_vector_type(4))) float f32x4;
typedef __attribute__((ext_vector_type(16))) float f32x16;
typedef __attribute__((ext_vector_type(4))) unsigned short ushort4v;
typedef unsigned long long u64;

__device__ __forceinline__ ushort f16_bits(float f) {
    _Float16 h = (_Float16)f;                      // v_cvt_f16_f32, RNE
    return __builtin_bit_cast(unsigned short, h);
}

// async global->LDS 16B copy (one per lane; dest = wave base + lane*16)
__device__ __forceinline__ void gload16(const void* g, void* l) {
    __builtin_amdgcn_global_load_lds(
        (const __attribute__((address_space(1))) unsigned int*)g,
        (__attribute__((address_space(3))) unsigned int*)l, 16, 0, 0);
}

// ---------------------------------------------------------------------------
// f32 -> f16 convert (RNE)
// ---------------------------------------------------------------------------
__global__ void cvt16(const float* __restrict__ src, ushort* __restrict__ dst, int n)
{
    int i = (blockIdx.x*256 + threadIdx.x)*4;
    if (i >= n) return;
    float4 v = *(const float4*)(src + i);
    ushort4v o;
    o[0] = f16_bits(v.x); o[1] = f16_bits(v.y);
    o[2] = f16_bits(v.z); o[3] = f16_bits(v.w);
    *(ushort4v*)(dst + i) = o;
}

// ---------------------------------------------------------------------------
// Single-pass f16 MFMA GEMM: C[M,512] = A[M,512] @ W[512,512]^T (+bias).
// 128x128 tile, BK=64, 4 waves x (64x64), mfma_f32_32x32x16_f16.
// LDS 32KB: A plane [8][128][8 f16] @0, B plane @16KB (chunk-planar:
// conflict-free ds_read_b128 AND linear global_load_lds dest).
// 1D grid, yz-fastest decode + bijective XCD swizzle.
// ---------------------------------------------------------------------------
__global__ __launch_bounds__(256, 4)
void gemm_h(const ushort* __restrict__ A, const ushort* __restrict__ W,
            const float* __restrict__ bias, float* __restrict__ C,
            int wplane, long cplane, int nyz, int nz)
{
    __shared__ ushort smem[16384];   // 2 planes x [8][128][8] = 32 KB
    const int tid = threadIdx.x;
    const int wave = tid >> 6, lane = tid & 63;
    const int wm = wave >> 1, wn = wave & 1;
    const int l31 = lane & 31, lg = lane >> 5;

    // bijective XCD swizzle (m204), then yz-fastest decode
    int nwg = gridDim.x, orig = blockIdx.x;
    int q8 = nwg >> 3, r8 = nwg & 7, xcd = orig & 7, loc = orig >> 3;
    int wg = (xcd < r8 ? xcd*(q8+1) : r8*(q8+1) + (xcd-r8)*q8) + loc;
    int bx = wg / nyz, yz = wg - bx*nyz;
    int by = yz / nz,  z  = yz - by*nz;

    const int bm0 = bx * 128, bn0 = by * 128;
    const ushort* Wz = W + (size_t)z * wplane;
    float* Cz = C + (size_t)z * cplane;

    f32x16 acc[2][2];
    #pragma unroll
    for (int fi = 0; fi < 2; ++fi)
        #pragma unroll
        for (int fj = 0; fj < 2; ++fj)
            #pragma unroll
            for (int r = 0; r < 16; ++r) acc[fi][fj][r] = 0.f;

    for (int kt = 0; kt < D_; kt += 64) {
        // stage A (128x64 f16 = 16KB) + B (16KB): 8 x 16B chunks per thread
        #pragma unroll
        for (int i = 0; i < 8; ++i) {
            const int q = ((i & 3) << 8) | tid;   // chunk id [0,1024)
            const int row = q & 127, c = q >> 7;  // LDS layout [c][row][8]
            ushort* dst = smem + ((i >> 2) << 13) + q*8;
            if (i < 4) {
                int gr = bm0 + row;
                if (gr < M_) gload16(A + (size_t)gr*D_ + kt + c*8, dst);
            } else {
                int gc = bn0 + row;
                gload16(Wz + (size_t)gc*D_ + kt + c*8, dst);
            }
        }
        __syncthreads();                          // vmcnt drain + barrier
        #pragma unroll
        for (int s = 0; s < 4; ++s) {
            const int cA = (s << 1) | lg;         // chunk: K-slice [cA*8, cA*8+8)
            f16x8 av[2], bv[2];
            #pragma unroll
            for (int f = 0; f < 2; ++f) {
                av[f] = *(const f16x8*)&smem[        (cA*128 + wm*64 + f*32 + l31)*8];
                bv[f] = *(const f16x8*)&smem[8192 + (cA*128 + wn*64 + f*32 + l31)*8];
            }
            #pragma unroll
            for (int fi = 0; fi < 2; ++fi)
                #pragma unroll
                for (int fj = 0; fj < 2; ++fj)
                    acc[fi][fj] = __builtin_amdgcn_mfma_f32_32x32x16_f16(av[fi], bv[fj], acc[fi][fj], 0, 0, 0);
        }
        __syncthreads();                          // protect LDS overwrite
    }
    // epilogue: C/D layout col=lane&31, row=(reg&3)+8*(reg>>2)+4*(lane>>5)
    #pragma unroll
    for (int fi = 0; fi < 2; ++fi)
        #pragma unroll
        for (int fj = 0; fj < 2; ++fj) {
            int gcol = bn0 + wn*64 + fj*32 + l31;
            float bv = bias ? bias[gcol] : 0.f;
            #pragma unroll
            for (int r = 0; r < 16; ++r) {
                int grow = bm0 + wm*64 + fi*32 + (r&3) + 8*(r>>2) + 4*lg;
                if (grow < M_)
                    Cz[(size_t)grow*D_ + gcol] = acc[fi][fj][r] + bv;
            }
        }
}

// ---------------------------------------------------------------------------
// LIF over T=4 for q,k,v -> packed 64-bit spike masks (bit d of word (t,b,n,h)).
// Flags near-threshold chains for f64 fixup.
// ---------------------------------------------------------------------------
__global__ void lif3_bits(const float* __restrict__ qkv, u64* __restrict__ bits3,
                          unsigned int* cnt, unsigned int* list)
{
    int idx = blockIdx.x*256 + threadIdx.x;        // [0, 3*PLANE)
    int tsr = idx / PLANE;
    int rem = idx - tsr*PLANE;
    const float* buf = qkv + (size_t)tsr*TENSOR_ELEMS;
    u64* bits = bits3 + (size_t)tsr*MH;
    int r = rem >> 9, h = (rem >> 6) & 7;          // wave-uniform
    int lane = threadIdx.x & 63;                   // = d
    float v = 0.f; bool flag = false;
    #pragma unroll
    for (int t = 0; t < T_; ++t) {
        float x = buf[(size_t)t*PLANE + rem];
        float hh = v + (x - v)*0.5f;
        bool s = hh >= 1.0f;
        flag |= fabsf(hh - 1.0f) < FLAG_TOL;
        u64 m = __ballot(s);
        if (lane == 0) bits[(size_t)(t*BN_ + r)*H_ + h] = m;
        v = s ? 0.0f : hh;
    }
    if (flag) {
        unsigned int p = atomicAdd(cnt, 1u);
        if (p < MAXFLAG) list[p] = (unsigned int)idx;
    }
}

// f64 exact recompute of flagged chains; corrects single bits in the masks.
__global__ void fixup_qkv(const float* __restrict__ x,
                          const float* __restrict__ Wq, const float* __restrict__ Wk,
                          const float* __restrict__ Wv,
                          u64* __restrict__ bits3,
                          const unsigned int* cnt, const unsigned int* list)
{
    unsigned int n = *cnt; if (n > MAXFLAG) n = MAXFLAG;
    int lane = threadIdx.x;                        // 64 threads = 1 wave
    for (unsigned int ii = blockIdx.x; ii < n; ii += gridDim.x) {
        unsigned int id = list[ii];
        int tsr = id / PLANE;
        int rem = id - tsr*PLANE;
        int r = rem >> 9, e = rem & (D_-1);
        const float* W = (tsr==0) ? Wq : (tsr==1 ? Wk : Wv);
        u64* bits = bits3 + (size_t)tsr*MH;
        double dots[T_];
        #pragma unroll
        for (int t = 0; t < T_; ++t) {
            const float* xr = x + (size_t)(t*BN_ + r)*D_;
            const float* wr = W + (size_t)e*D_;
            double p = 0.0;
            for (int d = lane; d < D_; d += 64)
                p += (double)xr[d] * (double)wr[d];
            #pragma unroll
            for (int off = 32; off > 0; off >>= 1)
                p += __shfl_down(p, off);
            dots[t] = p;
        }
        if (lane == 0) {
            double v = 0.0;
            u64 bit = 1ull << (e & 63);
            #pragma unroll
            for (int t = 0; t < T_; ++t) {
                double hh = v + (dots[t] - v)/2.0;
                bool s = hh >= 1.0;
                size_t w = (size_t)(t*BN_ + r)*H_ + (e >> 6);
                if (s) atomicOr(&bits[w], bit);
                else   atomicAnd(&bits[w], ~bit);
                v = s ? 0.0 : hh;
            }
        }
    }
}

// ---------------------------------------------------------------------------
// MFMA attention from packed spike masks (exact integer math).
// ---------------------------------------------------------------------------
#define NP 208   // 13 * 16 (padded N)
#define QSTR 72  // LDS row stride (ushorts) for Q/K tiles
#define JP 224   // 7 * 32 (padded j for PV K-dim)
#define VSTR 232 // LDS row stride for Vt / S strips

__global__ __launch_bounds__(256)
void attn_qk(const u64* __restrict__ qbits, const u64* __restrict__ kbits,
             float* __restrict__ attn_out)
{
    __shared__ ushort Qs[NP][QSTR];
    __shared__ ushort Ks[NP][QSTR];
    int tb = blockIdx.x, h = blockIdx.y;
    int tid = threadIdx.x, wave = tid >> 6, lane = tid & 63;

    for (int idx = tid; idx < NP*16; idx += 256) {
        int j = idx >> 4, d4 = (idx & 15) << 2;
        ushort qv[4] = {0,0,0,0}, kv[4] = {0,0,0,0};
        if (j < N_) {
            size_t w = ((size_t)tb*N_ + j)*H_ + h;
            u64 qw = qbits[w], kw = kbits[w];
            #pragma unroll
            for (int r = 0; r < 4; ++r) {
                qv[r] = ((qw >> (d4+r)) & 1ull) ? 0x3F80 : 0;
                kv[r] = ((kw >> (d4+r)) & 1ull) ? 0x3F80 : 0;
            }
        }
        #pragma unroll
        for (int r = 0; r < 4; ++r) { Qs[j][d4+r] = qv[r]; Ks[j][d4+r] = kv[r]; }
    }
    __syncthreads();

    const int il = lane & 15;
    const int kk = (lane >> 4) << 3;
    const int ig = (lane >> 4) << 2;
    const size_t amap = ((size_t)tb*H_ + h)*(size_t)(N_*N_);

    for (int it = wave; it < 13; it += 4) {
        int i0 = it << 4;
        short8v a0 = *(const short8v*)&Qs[i0 + il][kk];
        short8v a1 = *(const short8v*)&Qs[i0 + il][kk + 32];
        for (int jt = 0; jt < 13; ++jt) {
            int j0 = jt << 4;
            short8v b0 = *(const short8v*)&Ks[j0 + il][kk];
            short8v b1 = *(const short8v*)&Ks[j0 + il][kk + 32];
            f32x4 c = {0.f, 0.f, 0.f, 0.f};
            c = __builtin_amdgcn_mfma_f32_16x16x32_bf16(a0, b0, c, 0, 0, 0);
            c = __builtin_amdgcn_mfma_f32_16x16x32_bf16(a1, b1, c, 0, 0, 0);
            int j = j0 + il;
            if (j < N_) {
                #pragma unroll
                for (int r = 0; r < 4; ++r) {
                    int i = i0 + ig + r;
                    if (i < N_) attn_out[amap + (size_t)i*N_ + j] = c[r]*0.125f;
                }
            }
        }
    }
}

// O = attn @ V. Writes O as f16 (EXACT: O = m/8, m <= 788 < 2048) for the
// proj GEMM, and as f32 for the exact f64 fixup path.
__global__ __launch_bounds__(256)
void attn_pv(const float* __restrict__ attn, const u64* __restrict__ vbits,
             ushort* __restrict__ of16, float* __restrict__ of32)
{
    __shared__ ushort Vt[DH][VSTR];
    __shared__ ushort Ss[4][16][VSTR];
    int tb = blockIdx.x, h = blockIdx.y;
    int tid = threadIdx.x, wave = tid >> 6, lane = tid & 63;

    for (int idx = tid; idx < JP*16; idx += 256) {
        int j = idx >> 4, d4 = (idx & 15) << 2;
        ushort vv[4] = {0,0,0,0};
        if (j < N_) {
            u64 vw = vbits[((size_t)tb*N_ + j)*H_ + h];
            #pragma unroll
            for (int r = 0; r < 4; ++r)
                vv[r] = ((vw >> (d4+r)) & 1ull) ? 0x3F80 : 0;
        }
        Vt[d4+0][j]=vv[0]; Vt[d4+1][j]=vv[1]; Vt[d4+2][j]=vv[2]; Vt[d4+3][j]=vv[3];
    }
    for (int idx = lane; idx < 16*16; idx += 64)
        Ss[wave][idx >> 4][208 + (idx & 15)] = 0;
    __syncthreads();

    const int il = lane & 15, kk = (lane >> 4) << 3, ig = (lane >> 4) << 2;
    const size_t amap = ((size_t)tb*H_ + h)*(size_t)(N_*N_);

    for (int it = wave; it < 13; it += 4) {
        int i0 = it << 4;
        #pragma unroll 4
        for (int r = 0; r < 16; ++r) {
            int i = i0 + r;
            bool live = i < N_;
            const float* arow = attn + amap + (size_t)i*N_;
            for (int c = lane; c < NP; c += 64) {
                float av = (live && c < N_) ? arow[c] : 0.f;
                Ss[wave][r][c] = (ushort)(__float_as_uint(av) >> 16);
            }
        }
        #pragma unroll
        for (int dt = 0; dt < 4; ++dt) {
            f32x4 o = {0.f, 0.f, 0.f, 0.f};
            #pragma unroll
            for (int kt = 0; kt < 7; ++kt) {
                short8v a = *(const short8v*)&Ss[wave][il][kt*32 + kk];
                short8v b = *(const short8v*)&Vt[dt*16 + il][kt*32 + kk];
                o = __builtin_amdgcn_mfma_f32_16x16x32_bf16(a, b, o, 0, 0, 0);
            }
            #pragma unroll
            for (int r = 0; r < 4; ++r) {
                int i = i0 + ig + r;
                if (i < N_) {
                    size_t oidx = ((size_t)tb*N_ + i)*D_ + (size_t)h*DH + dt*16 + il;
                    float ov = o[r];
                    of16[oidx] = f16_bits(ov);
                    of32[oidx] = ov;
                }
            }
        }
    }
}

// ---------------------------------------------------------------------------
// Final LIF (proj -> output spikes f32) with flagging, and its f64 fixup.
// ---------------------------------------------------------------------------
__global__ void lif_proj(const float* __restrict__ proj, float* __restrict__ outp,
                         unsigned int* cnt, unsigned int* list)
{
    int idx = blockIdx.x*256 + threadIdx.x;        // [0, PLANE)
    float v = 0.f; bool flag = false;
    #pragma unroll
    for (int t = 0; t < T_; ++t) {
        float xv = proj[(size_t)t*PLANE + idx];
        float h = v + (xv - v)*0.5f;
        bool s = h >= 1.0f;
        flag |= fabsf(h - 1.0f) < FLAG_TOL;
        outp[(size_t)t*PLANE + idx] = s ? 1.0f : 0.0f;
        v = s ? 0.0f : h;
    }
    if (flag) {
        unsigned int p = atomicAdd(cnt, 1u);
        if (p < MAXFLAG) list[p] = (unsigned int)idx;
    }
}

__global__ void fixup_proj(const float* __restrict__ of32, const float* __restrict__ Wp,
                           const float* __restrict__ bp, float* __restrict__ outp,
                           const unsigned int* cnt, const unsigned int* list)
{
    unsigned int n = *cnt; if (n > MAXFLAG) n = MAXFLAG;
    int lane = threadIdx.x;
    for (unsigned int ii = blockIdx.x; ii < n; ii += gridDim.x) {
        unsigned int rem = list[ii];
        int r = rem >> 9, e = rem & (D_-1);
        double dots[T_];
        #pragma unroll
        for (int t = 0; t < T_; ++t) {
            const float* ar = of32 + (size_t)(t*BN_ + r)*D_;
            const float* wr = Wp + (size_t)e*D_;
            double p = 0.0;
            for (int d = lane; d < D_; d += 64)
                p += (double)ar[d] * (double)wr[d];
            #pragma unroll
            for (int off = 32; off > 0; off >>= 1)
                p += __shfl_down(p, off);
            dots[t] = p;
        }
        if (lane == 0) {
            double v = 0.0;
            #pragma unroll
            for (int t = 0; t < T_; ++t) {
                double xt = dots[t] + (double)bp[e];
                double h = v + (xt - v)/2.0;
                bool s = h >= 1.0;
                outp[(size_t)t*PLANE + rem] = s ? 1.0f : 0.0f;
                v = s ? 0.0 : h;
            }
        }
    }
}

// ---------------------------------------------------------------------------
extern "C" void kernel_launch(void* const* d_in, const int* in_sizes, int n_in,
                              void* d_out, int out_size, void* d_ws, size_t ws_size,
                              hipStream_t stream)
{
    const float* x  = (const float*)d_in[0];
    const float* Wq = (const float*)d_in[1];
    const float* Wk = (const float*)d_in[2];
    const float* Wv = (const float*)d_in[3];
    const float* Wp = (const float*)d_in[4];
    const float* bp = (const float*)d_in[5];
    float* out_spk  = (float*)d_out;                       // (T,B,N,D) spikes
    float* attn_out = (float*)d_out + TENSOR_ELEMS;        // (T,B,H,N,N)

    char* ws = (char*)d_ws;
    const size_t BUFB = (size_t)TENSOR_ELEMS * sizeof(float);   // 25.8 MB
    if (ws_size < 4*BUFB) return;
    // R0: q f32 -> pbuf (proj f32 out)
    float* qkv  = (float*)ws;
    float* pbuf = qkv;
    // R1: k f32 -> O f32 (fixup operand)
    float* of32 = (float*)(ws + 1*BUFB);
    // R2: v f32 -> O f16 (proj GEMM operand)
    ushort* of16 = (ushort*)(ws + 2*BUFB);
    // R3: xh f16 | w3h | wph | bits | cnts+lists (all phases disjoint in time)
    char* r3 = ws + 3*BUFB;
    ushort* xh   = (ushort*)r3;                            // 12.9 MB
    ushort* w3h  = (ushort*)(r3 + (13u<<20));              // 1.5 MB
    ushort* wph  = (ushort*)(r3 + (15u<<20));              // 0.5 MB
    u64*    bits3 = (u64*)(r3 + (16u<<20));                // 2.42 MB
    u64*    qbits = bits3;
    u64*    kbits = bits3 + MH;
    u64*    vbits = bits3 + 2*(size_t)MH;
    unsigned int* cnt0  = (unsigned int*)(r3 + (19u<<20));
    unsigned int* cnt1  = cnt0 + 1;
    unsigned int* list0 = cnt0 + 2;
    unsigned int* list1 = list0 + MAXFLAG;

    hipMemsetAsync(cnt0, 0, 8, stream);

    // f32 -> f16 conversions
    cvt16<<<TENSOR_ELEMS/1024, 256, 0, stream>>>(x, xh, TENSOR_ELEMS);
    cvt16<<<WELEMS/1024, 256, 0, stream>>>(Wq, w3h,            WELEMS);
    cvt16<<<WELEMS/1024, 256, 0, stream>>>(Wk, w3h +   WELEMS, WELEMS);
    cvt16<<<WELEMS/1024, 256, 0, stream>>>(Wv, w3h + 2*WELEMS, WELEMS);
    cvt16<<<WELEMS/1024, 256, 0, stream>>>(Wp, wph,            WELEMS);

    // QKV projections: 1D grid, x-tiles x (y=4 col-blocks x z=3 weights)
    gemm_h<<<99*12, 256, 0, stream>>>(
        xh, w3h, nullptr, qkv, WELEMS, (long)TENSOR_ELEMS, 12, 3);

    // LIF -> packed spike masks + flags, exact f64 fixup of boundary chains
    lif3_bits<<<3*PLANE/256, 256, 0, stream>>>(qkv, bits3, cnt0, list0);
    fixup_qkv<<<4096, 64, 0, stream>>>(x, Wq, Wk, Wv, bits3, cnt0, list0);

    // attention (exact integer math via bf16 MFMA on 0/1 spikes)
    attn_qk<<<dim3(T_*B_, H_), 256, 0, stream>>>(qbits, kbits, attn_out);
    attn_pv<<<dim3(T_*B_, H_), 256, 0, stream>>>(attn_out, vbits, of16, of32);

    // output projection + bias, LIF + flags, f64 fixup
    gemm_h<<<99*4, 256, 0, stream>>>(
        of16, wph, bp, pbuf, 0, 0, 4, 1);
    lif_proj<<<PLANE/256, 256, 0, stream>>>(pbuf, out_spk, cnt1, list1);
    fixup_proj<<<2048, 64, 0, stream>>>(of32, Wp, bp, out_spk, cnt1, list1);
}

// Round 6
// 420.068 us; speedup vs baseline: 1.4008x; 1.4008x over previous
//
#include <hip/hip_runtime.h>
#include <stdint.h>

// Problem constants
#define T_ 4
#define B_ 16
#define N_ 197
#define D_ 512
#define H_ 8
#define DH 64
#define BN_ (B_*N_)              // 3152 rows per timestep
#define PLANE (BN_*D_)           // 1,613,824 elems per t-plane
#define M_ (T_*BN_)              // 12608 GEMM rows
#define TENSOR_ELEMS (T_*PLANE)  // 6,455,296 elems per (T,B,N,D) tensor
#define WELEMS (D_*D_)           // 262,144
#define MH (M_*H_)               // 100,864 bitmask words per tensor
#define FLAG_TOL 6e-3f           // ~13 sigma of single-pass f16 dot error
#define NFW3 (3*PLANE/64)        // 75,648 flag words (qkv)
#define NFWP (PLANE/64)          // 25,216 flag words (proj)

typedef __attribute__((ext_vector_type(8))) short short8v;
typedef __attribute__((ext_vector_type(8))) _Float16 f16x8;
typedef __attribute__((ext_vector_type(4))) float f32x4;
typedef __attribute__((ext_vector_type(16))) float f32x16;
typedef __attribute__((ext_vector_type(4))) unsigned short ushort4v;
typedef unsigned long long u64;

__device__ __forceinline__ ushort f16_bits(float f) {
    _Float16 h = (_Float16)f;                      // v_cvt_f16_f32, RNE
    return __builtin_bit_cast(unsigned short, h);
}

// async global->LDS 16B copy (one per lane; dest = wave base + lane*16)
__device__ __forceinline__ void gload16(const void* g, void* l) {
    __builtin_amdgcn_global_load_lds(
        (const __attribute__((address_space(1))) unsigned int*)g,
        (__attribute__((address_space(3))) unsigned int*)l, 16, 0, 0);
}

// ---------------------------------------------------------------------------
// f32 -> f16 convert (RNE)
// ---------------------------------------------------------------------------
__global__ void cvt16(const float* __restrict__ src, ushort* __restrict__ dst, int n)
{
    int i = (blockIdx.x*256 + threadIdx.x)*4;
    if (i >= n) return;
    float4 v = *(const float4*)(src + i);
    ushort4v o;
    o[0] = f16_bits(v.x); o[1] = f16_bits(v.y);
    o[2] = f16_bits(v.z); o[3] = f16_bits(v.w);
    *(ushort4v*)(dst + i) = o;
}

// ---------------------------------------------------------------------------
// Single-pass f16 MFMA GEMM: C[M,512] = A[M,512] @ W[512,512]^T (+bias).
// 128x128 tile, BK=64, 4 waves x (64x64), mfma_f32_32x32x16_f16.
// LDS 32KB chunk-planar (conflict-free ds_read_b128 + linear gload_lds dest).
// 1D grid, yz-fastest decode + bijective XCD swizzle.
// ---------------------------------------------------------------------------
__global__ __launch_bounds__(256, 4)
void gemm_h(const ushort* __restrict__ A, const ushort* __restrict__ W,
            const float* __restrict__ bias, float* __restrict__ C,
            int wplane, long cplane, int nyz, int nz)
{
    __shared__ ushort smem[16384];   // 2 planes x [8][128][8] = 32 KB
    const int tid = threadIdx.x;
    const int wave = tid >> 6, lane = tid & 63;
    const int wm = wave >> 1, wn = wave & 1;
    const int l31 = lane & 31, lg = lane >> 5;

    // bijective XCD swizzle (m204), then yz-fastest decode
    int nwg = gridDim.x, orig = blockIdx.x;
    int q8 = nwg >> 3, r8 = nwg & 7, xcd = orig & 7, loc = orig >> 3;
    int wg = (xcd < r8 ? xcd*(q8+1) : r8*(q8+1) + (xcd-r8)*q8) + loc;
    int bx = wg / nyz, yz = wg - bx*nyz;
    int by = yz / nz,  z  = yz - by*nz;

    const int bm0 = bx * 128, bn0 = by * 128;
    const ushort* Wz = W + (size_t)z * wplane;
    float* Cz = C + (size_t)z * cplane;

    f32x16 acc[2][2];
    #pragma unroll
    for (int fi = 0; fi < 2; ++fi)
        #pragma unroll
        for (int fj = 0; fj < 2; ++fj)
            #pragma unroll
            for (int r = 0; r < 16; ++r) acc[fi][fj][r] = 0.f;

    for (int kt = 0; kt < D_; kt += 64) {
        // stage A (128x64 f16 = 16KB) + B (16KB): 8 x 16B chunks per thread
        #pragma unroll
        for (int i = 0; i < 8; ++i) {
            const int q = ((i & 3) << 8) | tid;   // chunk id [0,1024)
            const int row = q & 127, c = q >> 7;  // LDS layout [c][row][8]
            ushort* dst = smem + ((i >> 2) << 13) + q*8;
            if (i < 4) {
                int gr = bm0 + row;
                if (gr < M_) gload16(A + (size_t)gr*D_ + kt + c*8, dst);
            } else {
                int gc = bn0 + row;
                gload16(Wz + (size_t)gc*D_ + kt + c*8, dst);
            }
        }
        __syncthreads();                          // vmcnt drain + barrier
        #pragma unroll
        for (int s = 0; s < 4; ++s) {
            const int cA = (s << 1) | lg;         // chunk: K-slice [cA*8, cA*8+8)
            f16x8 av[2], bv[2];
            #pragma unroll
            for (int f = 0; f < 2; ++f) {
                av[f] = *(const f16x8*)&smem[        (cA*128 + wm*64 + f*32 + l31)*8];
                bv[f] = *(const f16x8*)&smem[8192 + (cA*128 + wn*64 + f*32 + l31)*8];
            }
            #pragma unroll
            for (int fi = 0; fi < 2; ++fi)
                #pragma unroll
                for (int fj = 0; fj < 2; ++fj)
                    acc[fi][fj] = __builtin_amdgcn_mfma_f32_32x32x16_f16(av[fi], bv[fj], acc[fi][fj], 0, 0, 0);
        }
        __syncthreads();                          // protect LDS overwrite
    }
    // epilogue: C/D layout col=lane&31, row=(reg&3)+8*(reg>>2)+4*(lane>>5)
    #pragma unroll
    for (int fi = 0; fi < 2; ++fi)
        #pragma unroll
        for (int fj = 0; fj < 2; ++fj) {
            int gcol = bn0 + wn*64 + fj*32 + l31;
            float bv = bias ? bias[gcol] : 0.f;
            #pragma unroll
            for (int r = 0; r < 16; ++r) {
                int grow = bm0 + wm*64 + fi*32 + (r&3) + 8*(r>>2) + 4*lg;
                if (grow < M_)
                    Cz[(size_t)grow*D_ + gcol] = acc[fi][fj][r] + bv;
            }
        }
}

// ---------------------------------------------------------------------------
// LIF over T=4 for q,k,v -> packed 64-bit spike masks. Flags near-threshold
// chains into a dense per-wave bitmap (NO atomics; every wave writes its word).
// ---------------------------------------------------------------------------
__global__ void lif3_bits(const float* __restrict__ qkv, u64* __restrict__ bits3,
                          u64* __restrict__ flagmap)
{
    int idx = blockIdx.x*256 + threadIdx.x;        // [0, 3*PLANE)
    int tsr = idx / PLANE;
    int rem = idx - tsr*PLANE;
    const float* buf = qkv + (size_t)tsr*TENSOR_ELEMS;
    u64* bits = bits3 + (size_t)tsr*MH;
    int r = rem >> 9, h = (rem >> 6) & 7;          // wave-uniform
    int lane = threadIdx.x & 63;                   // = d
    float v = 0.f; bool flag = false;
    #pragma unroll
    for (int t = 0; t < T_; ++t) {
        float x = buf[(size_t)t*PLANE + rem];
        float hh = v + (x - v)*0.5f;
        bool s = hh >= 1.0f;
        flag |= fabsf(hh - 1.0f) < FLAG_TOL;
        u64 m = __ballot(s);
        if (lane == 0) bits[(size_t)(t*BN_ + r)*H_ + h] = m;
        v = s ? 0.0f : hh;
    }
    u64 fm = __ballot(flag);
    if (lane == 0) flagmap[idx >> 6] = fm;
}

// f64 exact recompute of flagged chains (bitmap scan); corrects mask bits.
__global__ void fixup_qkv(const float* __restrict__ x,
                          const float* __restrict__ Wq, const float* __restrict__ Wk,
                          const float* __restrict__ Wv,
                          u64* __restrict__ bits3, const u64* __restrict__ flagmap)
{
    int lane = threadIdx.x;                        // 64 threads = 1 wave
    for (int w = blockIdx.x; w < NFW3; w += gridDim.x) {
        u64 fm = flagmap[w];
        while (fm) {
            int bit = __ffsll((long long)fm) - 1;
            fm &= fm - 1;
            int id = (w << 6) + bit;
            int tsr = id / PLANE;
            int rem = id - tsr*PLANE;
            int r = rem >> 9, e = rem & (D_-1);
            const float* W = (tsr==0) ? Wq : (tsr==1 ? Wk : Wv);
            u64* bits = bits3 + (size_t)tsr*MH;
            double dots[T_];
            #pragma unroll
            for (int t = 0; t < T_; ++t) {
                const float* xr = x + (size_t)(t*BN_ + r)*D_;
                const float* wr = W + (size_t)e*D_;
                double p = 0.0;
                for (int d = lane; d < D_; d += 64)
                    p += (double)xr[d] * (double)wr[d];
                #pragma unroll
                for (int off = 32; off > 0; off >>= 1)
                    p += __shfl_down(p, off);
                dots[t] = p;
            }
            if (lane == 0) {
                double v = 0.0;
                u64 b = 1ull << (e & 63);
                #pragma unroll
                for (int t = 0; t < T_; ++t) {
                    double hh = v + (dots[t] - v)/2.0;
                    bool s = hh >= 1.0;
                    size_t wd = (size_t)(t*BN_ + r)*H_ + (e >> 6);
                    if (s) atomicOr(&bits[wd], b);
                    else   atomicAnd(&bits[wd], ~b);
                    v = s ? 0.0 : hh;
                }
            }
        }
    }
}

// ---------------------------------------------------------------------------
// MFMA attention from packed spike masks (exact integer math).
// ---------------------------------------------------------------------------
#define NP 208   // 13 * 16 (padded N)
#define QSTR 72  // LDS row stride (ushorts) for Q/K tiles
#define JP 224   // 7 * 32 (padded j for PV K-dim)
#define VSTR 232 // LDS row stride for Vt / S strips

__global__ __launch_bounds__(256)
void attn_qk(const u64* __restrict__ qbits, const u64* __restrict__ kbits,
             float* __restrict__ attn_out)
{
    __shared__ ushort Qs[NP][QSTR];
    __shared__ ushort Ks[NP][QSTR];
    int tb = blockIdx.x, h = blockIdx.y;
    int tid = threadIdx.x, wave = tid >> 6, lane = tid & 63;

    for (int idx = tid; idx < NP*16; idx += 256) {
        int j = idx >> 4, d4 = (idx & 15) << 2;
        ushort qv[4] = {0,0,0,0}, kv[4] = {0,0,0,0};
        if (j < N_) {
            size_t w = ((size_t)tb*N_ + j)*H_ + h;
            u64 qw = qbits[w], kw = kbits[w];
            #pragma unroll
            for (int r = 0; r < 4; ++r) {
                qv[r] = ((qw >> (d4+r)) & 1ull) ? 0x3F80 : 0;
                kv[r] = ((kw >> (d4+r)) & 1ull) ? 0x3F80 : 0;
            }
        }
        #pragma unroll
        for (int r = 0; r < 4; ++r) { Qs[j][d4+r] = qv[r]; Ks[j][d4+r] = kv[r]; }
    }
    __syncthreads();

    const int il = lane & 15;
    const int kk = (lane >> 4) << 3;
    const int ig = (lane >> 4) << 2;
    const size_t amap = ((size_t)tb*H_ + h)*(size_t)(N_*N_);

    for (int it = wave; it < 13; it += 4) {
        int i0 = it << 4;
        short8v a0 = *(const short8v*)&Qs[i0 + il][kk];
        short8v a1 = *(const short8v*)&Qs[i0 + il][kk + 32];
        for (int jt = 0; jt < 13; ++jt) {
            int j0 = jt << 4;
            short8v b0 = *(const short8v*)&Ks[j0 + il][kk];
            short8v b1 = *(const short8v*)&Ks[j0 + il][kk + 32];
            f32x4 c = {0.f, 0.f, 0.f, 0.f};
            c = __builtin_amdgcn_mfma_f32_16x16x32_bf16(a0, b0, c, 0, 0, 0);
            c = __builtin_amdgcn_mfma_f32_16x16x32_bf16(a1, b1, c, 0, 0, 0);
            int j = j0 + il;
            if (j < N_) {
                #pragma unroll
                for (int r = 0; r < 4; ++r) {
                    int i = i0 + ig + r;
                    if (i < N_) attn_out[amap + (size_t)i*N_ + j] = c[r]*0.125f;
                }
            }
        }
    }
}

// O = attn @ V. Writes O as f16 (EXACT: O = m/8, m <= 788 < 2048) for the
// proj GEMM, and as f32 for the exact f64 fixup path.
__global__ __launch_bounds__(256)
void attn_pv(const float* __restrict__ attn, const u64* __restrict__ vbits,
             ushort* __restrict__ of16, float* __restrict__ of32)
{
    __shared__ ushort Vt[DH][VSTR];
    __shared__ ushort Ss[4][16][VSTR];
    int tb = blockIdx.x, h = blockIdx.y;
    int tid = threadIdx.x, wave = tid >> 6, lane = tid & 63;

    for (int idx = tid; idx < JP*16; idx += 256) {
        int j = idx >> 4, d4 = (idx & 15) << 2;
        ushort vv[4] = {0,0,0,0};
        if (j < N_) {
            u64 vw = vbits[((size_t)tb*N_ + j)*H_ + h];
            #pragma unroll
            for (int r = 0; r < 4; ++r)
                vv[r] = ((vw >> (d4+r)) & 1ull) ? 0x3F80 : 0;
        }
        Vt[d4+0][j]=vv[0]; Vt[d4+1][j]=vv[1]; Vt[d4+2][j]=vv[2]; Vt[d4+3][j]=vv[3];
    }
    for (int idx = lane; idx < 16*16; idx += 64)
        Ss[wave][idx >> 4][208 + (idx & 15)] = 0;
    __syncthreads();

    const int il = lane & 15, kk = (lane >> 4) << 3, ig = (lane >> 4) << 2;
    const size_t amap = ((size_t)tb*H_ + h)*(size_t)(N_*N_);

    for (int it = wave; it < 13; it += 4) {
        int i0 = it << 4;
        #pragma unroll 4
        for (int r = 0; r < 16; ++r) {
            int i = i0 + r;
            bool live = i < N_;
            const float* arow = attn + amap + (size_t)i*N_;
            for (int c = lane; c < NP; c += 64) {
                float av = (live && c < N_) ? arow[c] : 0.f;
                Ss[wave][r][c] = (ushort)(__float_as_uint(av) >> 16);
            }
        }
        #pragma unroll
        for (int dt = 0; dt < 4; ++dt) {
            f32x4 o = {0.f, 0.f, 0.f, 0.f};
            #pragma unroll
            for (int kt = 0; kt < 7; ++kt) {
                short8v a = *(const short8v*)&Ss[wave][il][kt*32 + kk];
                short8v b = *(const short8v*)&Vt[dt*16 + il][kt*32 + kk];
                o = __builtin_amdgcn_mfma_f32_16x16x32_bf16(a, b, o, 0, 0, 0);
            }
            #pragma unroll
            for (int r = 0; r < 4; ++r) {
                int i = i0 + ig + r;
                if (i < N_) {
                    size_t oidx = ((size_t)tb*N_ + i)*D_ + (size_t)h*DH + dt*16 + il;
                    float ov = o[r];
                    of16[oidx] = f16_bits(ov);
                    of32[oidx] = ov;
                }
            }
        }
    }
}

// ---------------------------------------------------------------------------
// Final LIF (proj -> output spikes f32), flag bitmap (no atomics), f64 fixup.
// ---------------------------------------------------------------------------
__global__ void lif_proj(const float* __restrict__ proj, float* __restrict__ outp,
                         u64* __restrict__ flagmap)
{
    int idx = blockIdx.x*256 + threadIdx.x;        // [0, PLANE)
    int lane = threadIdx.x & 63;
    float v = 0.f; bool flag = false;
    #pragma unroll
    for (int t = 0; t < T_; ++t) {
        float xv = proj[(size_t)t*PLANE + idx];
        float h = v + (xv - v)*0.5f;
        bool s = h >= 1.0f;
        flag |= fabsf(h - 1.0f) < FLAG_TOL;
        outp[(size_t)t*PLANE + idx] = s ? 1.0f : 0.0f;
        v = s ? 0.0f : h;
    }
    u64 fm = __ballot(flag);
    if (lane == 0) flagmap[idx >> 6] = fm;
}

__global__ void fixup_proj(const float* __restrict__ of32, const float* __restrict__ Wp,
                           const float* __restrict__ bp, float* __restrict__ outp,
                           const u64* __restrict__ flagmap)
{
    int lane = threadIdx.x;
    for (int w = blockIdx.x; w < NFWP; w += gridDim.x) {
        u64 fm = flagmap[w];
        while (fm) {
            int bit = __ffsll((long long)fm) - 1;
            fm &= fm - 1;
            int rem = (w << 6) + bit;
            int r = rem >> 9, e = rem & (D_-1);
            double dots[T_];
            #pragma unroll
            for (int t = 0; t < T_; ++t) {
                const float* ar = of32 + (size_t)(t*BN_ + r)*D_;
                const float* wr = Wp + (size_t)e*D_;
                double p = 0.0;
                for (int d = lane; d < D_; d += 64)
                    p += (double)ar[d] * (double)wr[d];
                #pragma unroll
                for (int off = 32; off > 0; off >>= 1)
                    p += __shfl_down(p, off);
                dots[t] = p;
            }
            if (lane == 0) {
                double v = 0.0;
                #pragma unroll
                for (int t = 0; t < T_; ++t) {
                    double xt = dots[t] + (double)bp[e];
                    double h = v + (xt - v)/2.0;
                    bool s = h >= 1.0;
                    outp[(size_t)t*PLANE + rem] = s ? 1.0f : 0.0f;
                    v = s ? 0.0 : h;
                }
            }
        }
    }
}

// ---------------------------------------------------------------------------
extern "C" void kernel_launch(void* const* d_in, const int* in_sizes, int n_in,
                              void* d_out, int out_size, void* d_ws, size_t ws_size,
                              hipStream_t stream)
{
    const float* x  = (const float*)d_in[0];
    const float* Wq = (const float*)d_in[1];
    const float* Wk = (const float*)d_in[2];
    const float* Wv = (const float*)d_in[3];
    const float* Wp = (const float*)d_in[4];
    const float* bp = (const float*)d_in[5];
    float* out_spk  = (float*)d_out;                       // (T,B,N,D) spikes
    float* attn_out = (float*)d_out + TENSOR_ELEMS;        // (T,B,H,N,N)

    char* ws = (char*)d_ws;
    const size_t BUFB = (size_t)TENSOR_ELEMS * sizeof(float);   // 25.8 MB
    if (ws_size < 4*BUFB) return;
    // R0: q f32 -> pbuf (proj f32 out)
    float* qkv  = (float*)ws;
    float* pbuf = qkv;
    // R1: k f32 -> O f32 (fixup operand)
    float* of32 = (float*)(ws + 1*BUFB);
    // R2: v f32 -> O f16 (proj GEMM operand)
    ushort* of16 = (ushort*)(ws + 2*BUFB);
    // R3: xh f16 | w3h | wph | bits | flag bitmaps (phases disjoint in time)
    char* r3 = ws + 3*BUFB;
    ushort* xh   = (ushort*)r3;                            // 12.9 MB
    ushort* w3h  = (ushort*)(r3 + (13u<<20));              // 1.5 MB
    ushort* wph  = (ushort*)(r3 + (15u<<20));              // 0.5 MB
    u64*    bits3 = (u64*)(r3 + (16u<<20));                // 2.42 MB
    u64*    qbits = bits3;
    u64*    kbits = bits3 + MH;
    u64*    vbits = bits3 + 2*(size_t)MH;
    u64*    fmap3 = (u64*)(r3 + (19u<<20));                // 605 KB
    u64*    fmapp = (u64*)(r3 + (20u<<20));                // 202 KB

    // f32 -> f16 conversions
    cvt16<<<TENSOR_ELEMS/1024, 256, 0, stream>>>(x, xh, TENSOR_ELEMS);
    cvt16<<<WELEMS/1024, 256, 0, stream>>>(Wq, w3h,            WELEMS);
    cvt16<<<WELEMS/1024, 256, 0, stream>>>(Wk, w3h +   WELEMS, WELEMS);
    cvt16<<<WELEMS/1024, 256, 0, stream>>>(Wv, w3h + 2*WELEMS, WELEMS);
    cvt16<<<WELEMS/1024, 256, 0, stream>>>(Wp, wph,            WELEMS);

    // QKV projections: 1D grid, x-tiles x (y=4 col-blocks x z=3 weights)
    gemm_h<<<99*12, 256, 0, stream>>>(
        xh, w3h, nullptr, qkv, WELEMS, (long)TENSOR_ELEMS, 12, 3);

    // LIF -> packed spike masks + flag bitmap; exact f64 fixup of flagged chains
    lif3_bits<<<3*PLANE/256, 256, 0, stream>>>(qkv, bits3, fmap3);
    fixup_qkv<<<4096, 64, 0, stream>>>(x, Wq, Wk, Wv, bits3, fmap3);

    // attention (exact integer math via bf16 MFMA on 0/1 spikes)
    attn_qk<<<dim3(T_*B_, H_), 256, 0, stream>>>(qbits, kbits, attn_out);
    attn_pv<<<dim3(T_*B_, H_), 256, 0, stream>>>(attn_out, vbits, of16, of32);

    // output projection + bias, LIF + flag bitmap, f64 fixup
    gemm_h<<<99*4, 256, 0, stream>>>(
        of16, wph, bp, pbuf, 0, 0, 4, 1);
    lif_proj<<<PLANE/256, 256, 0, stream>>>(pbuf, out_spk, fmapp);
    fixup_proj<<<2048, 64, 0, stream>>>(of32, Wp, bp, out_spk, fmapp);
}

// Round 7
// 279.343 us; speedup vs baseline: 2.1065x; 1.5038x over previous
//
#include <hip/hip_runtime.h>
#include <stdint.h>

// Problem constants
#define T_ 4
#define B_ 16
#define N_ 197
#define D_ 512
#define H_ 8
#define DH 64
#define BN_ (B_*N_)              // 3152 rows per timestep
#define PLANE (BN_*D_)           // 1,613,824 elems per t-plane
#define M_ (T_*BN_)              // 12608 GEMM rows
#define TENSOR_ELEMS (T_*PLANE)  // 6,455,296 elems per (T,B,N,D) tensor
#define WELEMS (D_*D_)           // 262,144
#define MH (M_*H_)               // 100,864 bitmask words per tensor
#define FLAG_TOL 6e-3f           // ~13 sigma of single-pass f16 dot error
#define NFW3 (3*PLANE/64)        // 75,648 flag words (qkv)
#define NFWP (PLANE/64)          // 25,216 flag words (proj)

typedef __attribute__((ext_vector_type(8))) short short8v;
typedef __attribute__((ext_vector_type(8))) _Float16 f16x8;
typedef __attribute__((ext_vector_type(4))) float f32x4;
typedef __attribute__((ext_vector_type(16))) float f32x16;
typedef __attribute__((ext_vector_type(4))) unsigned short ushort4v;
typedef unsigned long long u64;

__device__ __forceinline__ ushort f16_bits(float f) {
    _Float16 h = (_Float16)f;                      // v_cvt_f16_f32, RNE
    return __builtin_bit_cast(unsigned short, h);
}

// async global->LDS 16B copy (one per lane; dest = wave base + lane*16)
__device__ __forceinline__ void gload16(const void* g, void* l) {
    __builtin_amdgcn_global_load_lds(
        (const __attribute__((address_space(1))) unsigned int*)g,
        (__attribute__((address_space(3))) unsigned int*)l, 16, 0, 0);
}

// ---------------------------------------------------------------------------
// f32 -> f16 convert (RNE)
// ---------------------------------------------------------------------------
__global__ void cvt16(const float* __restrict__ src, ushort* __restrict__ dst, int n)
{
    int i = (blockIdx.x*256 + threadIdx.x)*4;
    if (i >= n) return;
    float4 v = *(const float4*)(src + i);
    ushort4v o;
    o[0] = f16_bits(v.x); o[1] = f16_bits(v.y);
    o[2] = f16_bits(v.z); o[3] = f16_bits(v.w);
    *(ushort4v*)(dst + i) = o;
}

// ---------------------------------------------------------------------------
// Single-pass f16 MFMA GEMM: C[M,512] = A[M,512] @ W[512,512]^T (+bias).
// 128x128 tile, BK=64, 4 waves x (64x64), mfma_f32_32x32x16_f16.
// LDS 32KB chunk-planar (conflict-free ds_read_b128 + linear gload_lds dest).
// 1D grid, yz-fastest decode + bijective XCD swizzle.
// ---------------------------------------------------------------------------
__global__ __launch_bounds__(256, 4)
void gemm_h(const ushort* __restrict__ A, const ushort* __restrict__ W,
            const float* __restrict__ bias, float* __restrict__ C,
            int wplane, long cplane, int nyz, int nz)
{
    __shared__ ushort smem[16384];   // 2 planes x [8][128][8] = 32 KB
    const int tid = threadIdx.x;
    const int wave = tid >> 6, lane = tid & 63;
    const int wm = wave >> 1, wn = wave & 1;
    const int l31 = lane & 31, lg = lane >> 5;

    // bijective XCD swizzle (m204), then yz-fastest decode
    int nwg = gridDim.x, orig = blockIdx.x;
    int q8 = nwg >> 3, r8 = nwg & 7, xcd = orig & 7, loc = orig >> 3;
    int wg = (xcd < r8 ? xcd*(q8+1) : r8*(q8+1) + (xcd-r8)*q8) + loc;
    int bx = wg / nyz, yz = wg - bx*nyz;
    int by = yz / nz,  z  = yz - by*nz;

    const int bm0 = bx * 128, bn0 = by * 128;
    const ushort* Wz = W + (size_t)z * wplane;
    float* Cz = C + (size_t)z * cplane;

    f32x16 acc[2][2];
    #pragma unroll
    for (int fi = 0; fi < 2; ++fi)
        #pragma unroll
        for (int fj = 0; fj < 2; ++fj)
            #pragma unroll
            for (int r = 0; r < 16; ++r) acc[fi][fj][r] = 0.f;

    for (int kt = 0; kt < D_; kt += 64) {
        // stage A (128x64 f16 = 16KB) + B (16KB): 8 x 16B chunks per thread
        #pragma unroll
        for (int i = 0; i < 8; ++i) {
            const int q = ((i & 3) << 8) | tid;   // chunk id [0,1024)
            const int row = q & 127, c = q >> 7;  // LDS layout [c][row][8]
            ushort* dst = smem + ((i >> 2) << 13) + q*8;
            if (i < 4) {
                int gr = bm0 + row;
                if (gr < M_) gload16(A + (size_t)gr*D_ + kt + c*8, dst);
            } else {
                int gc = bn0 + row;
                gload16(Wz + (size_t)gc*D_ + kt + c*8, dst);
            }
        }
        __syncthreads();                          // vmcnt drain + barrier
        #pragma unroll
        for (int s = 0; s < 4; ++s) {
            const int cA = (s << 1) | lg;         // chunk: K-slice [cA*8, cA*8+8)
            f16x8 av[2], bv[2];
            #pragma unroll
            for (int f = 0; f < 2; ++f) {
                av[f] = *(const f16x8*)&smem[        (cA*128 + wm*64 + f*32 + l31)*8];
                bv[f] = *(const f16x8*)&smem[8192 + (cA*128 + wn*64 + f*32 + l31)*8];
            }
            #pragma unroll
            for (int fi = 0; fi < 2; ++fi)
                #pragma unroll
                for (int fj = 0; fj < 2; ++fj)
                    acc[fi][fj] = __builtin_amdgcn_mfma_f32_32x32x16_f16(av[fi], bv[fj], acc[fi][fj], 0, 0, 0);
        }
        __syncthreads();                          // protect LDS overwrite
    }
    // epilogue: C/D layout col=lane&31, row=(reg&3)+8*(reg>>2)+4*(lane>>5)
    #pragma unroll
    for (int fi = 0; fi < 2; ++fi)
        #pragma unroll
        for (int fj = 0; fj < 2; ++fj) {
            int gcol = bn0 + wn*64 + fj*32 + l31;
            float bv = bias ? bias[gcol] : 0.f;
            #pragma unroll
            for (int r = 0; r < 16; ++r) {
                int grow = bm0 + wm*64 + fi*32 + (r&3) + 8*(r>>2) + 4*lg;
                if (grow < M_)
                    Cz[(size_t)grow*D_ + gcol] = acc[fi][fj][r] + bv;
            }
        }
}

// ---------------------------------------------------------------------------
// LIF over T=4 for q,k,v -> packed 64-bit spike masks. Flags near-threshold
// chains into a dense per-wave bitmap (NO atomics).
// ---------------------------------------------------------------------------
__global__ void lif3_bits(const float* __restrict__ qkv, u64* __restrict__ bits3,
                          u64* __restrict__ flagmap)
{
    int idx = blockIdx.x*256 + threadIdx.x;        // [0, 3*PLANE)
    int tsr = idx / PLANE;
    int rem = idx - tsr*PLANE;
    const float* buf = qkv + (size_t)tsr*TENSOR_ELEMS;
    u64* bits = bits3 + (size_t)tsr*MH;
    int r = rem >> 9, h = (rem >> 6) & 7;          // wave-uniform
    int lane = threadIdx.x & 63;                   // = d
    float v = 0.f; bool flag = false;
    #pragma unroll
    for (int t = 0; t < T_; ++t) {
        float x = buf[(size_t)t*PLANE + rem];
        float hh = v + (x - v)*0.5f;
        bool s = hh >= 1.0f;
        flag |= fabsf(hh - 1.0f) < FLAG_TOL;
        u64 m = __ballot(s);
        if (lane == 0) bits[(size_t)(t*BN_ + r)*H_ + h] = m;
        v = s ? 0.0f : hh;
    }
    u64 fm = __ballot(flag);
    if (lane == 0) flagmap[idx >> 6] = fm;
}

// ---------------------------------------------------------------------------
// f64 exact recompute of flagged chains (bitmap scan, 4 independent waves per
// block). ILP-structured: W row hoisted (shared across t), all loads issued
// up-front, 4 reduction trees interleaved.
// ---------------------------------------------------------------------------
__global__ __launch_bounds__(256)
void fixup_qkv(const float* __restrict__ x,
               const float* __restrict__ Wq, const float* __restrict__ Wk,
               const float* __restrict__ Wv,
               u64* __restrict__ bits3, const u64* __restrict__ flagmap)
{
    const int lane = threadIdx.x & 63;
    const int wv = blockIdx.x*4 + (threadIdx.x >> 6);
    const int nw = gridDim.x*4;
    for (int w = wv; w < NFW3; w += nw) {
        u64 fm = flagmap[w];
        while (fm) {
            int bit = __ffsll((long long)fm) - 1;
            fm &= fm - 1;
            int id = (w << 6) + bit;
            int tsr = id / PLANE;
            int rem = id - tsr*PLANE;
            int r = rem >> 9, e = rem & (D_-1);
            const float* W = (tsr==0) ? Wq : (tsr==1 ? Wk : Wv);
            const float* wr = W + (size_t)e*D_;
            u64* bits = bits3 + (size_t)tsr*MH;
            float wv8[8];
            #pragma unroll
            for (int i = 0; i < 8; ++i) wv8[i] = wr[lane + 64*i];
            double dots[T_];
            #pragma unroll
            for (int t = 0; t < T_; ++t) {
                const float* xr = x + (size_t)(t*BN_ + r)*D_;
                float xv8[8];
                #pragma unroll
                for (int i = 0; i < 8; ++i) xv8[i] = xr[lane + 64*i];
                double p = 0.0;
                #pragma unroll
                for (int i = 0; i < 8; ++i) p += (double)xv8[i]*(double)wv8[i];
                dots[t] = p;
            }
            #pragma unroll
            for (int off = 32; off > 0; off >>= 1)
                #pragma unroll
                for (int t = 0; t < T_; ++t)
                    dots[t] += __shfl_down(dots[t], off);
            if (lane == 0) {
                double v = 0.0;
                u64 b = 1ull << (e & 63);
                #pragma unroll
                for (int t = 0; t < T_; ++t) {
                    double hh = v + (dots[t] - v)/2.0;
                    bool s = hh >= 1.0;
                    size_t wd = (size_t)(t*BN_ + r)*H_ + (e >> 6);
                    if (s) atomicOr(&bits[wd], b);
                    else   atomicAnd(&bits[wd], ~b);
                    v = s ? 0.0 : hh;
                }
            }
        }
    }
}

// ---------------------------------------------------------------------------
// MFMA attention from packed spike masks (exact integer math).
// ---------------------------------------------------------------------------
#define NP 208   // 13 * 16 (padded N)
#define QSTR 72  // LDS row stride (ushorts) for Q/K tiles
#define JP 224   // 7 * 32 (padded j for PV K-dim)
#define VSTR 232 // LDS row stride for Vt / S strips

__global__ __launch_bounds__(256)
void attn_qk(const u64* __restrict__ qbits, const u64* __restrict__ kbits,
             float* __restrict__ attn_out)
{
    __shared__ ushort Qs[NP][QSTR];
    __shared__ ushort Ks[NP][QSTR];
    int tb = blockIdx.x, h = blockIdx.y;
    int tid = threadIdx.x, wave = tid >> 6, lane = tid & 63;

    for (int idx = tid; idx < NP*16; idx += 256) {
        int j = idx >> 4, d4 = (idx & 15) << 2;
        ushort qv[4] = {0,0,0,0}, kv[4] = {0,0,0,0};
        if (j < N_) {
            size_t w = ((size_t)tb*N_ + j)*H_ + h;
            u64 qw = qbits[w], kw = kbits[w];
            #pragma unroll
            for (int r = 0; r < 4; ++r) {
                qv[r] = ((qw >> (d4+r)) & 1ull) ? 0x3F80 : 0;
                kv[r] = ((kw >> (d4+r)) & 1ull) ? 0x3F80 : 0;
            }
        }
        #pragma unroll
        for (int r = 0; r < 4; ++r) { Qs[j][d4+r] = qv[r]; Ks[j][d4+r] = kv[r]; }
    }
    __syncthreads();

    const int il = lane & 15;
    const int kk = (lane >> 4) << 3;
    const int ig = (lane >> 4) << 2;
    const size_t amap = ((size_t)tb*H_ + h)*(size_t)(N_*N_);

    for (int it = wave; it < 13; it += 4) {
        int i0 = it << 4;
        short8v a0 = *(const short8v*)&Qs[i0 + il][kk];
        short8v a1 = *(const short8v*)&Qs[i0 + il][kk + 32];
        for (int jt = 0; jt < 13; ++jt) {
            int j0 = jt << 4;
            short8v b0 = *(const short8v*)&Ks[j0 + il][kk];
            short8v b1 = *(const short8v*)&Ks[j0 + il][kk + 32];
            f32x4 c = {0.f, 0.f, 0.f, 0.f};
            c = __builtin_amdgcn_mfma_f32_16x16x32_bf16(a0, b0, c, 0, 0, 0);
            c = __builtin_amdgcn_mfma_f32_16x16x32_bf16(a1, b1, c, 0, 0, 0);
            int j = j0 + il;
            if (j < N_) {
                #pragma unroll
                for (int r = 0; r < 4; ++r) {
                    int i = i0 + ig + r;
                    if (i < N_) attn_out[amap + (size_t)i*N_ + j] = c[r]*0.125f;
                }
            }
        }
    }
}

// O = attn @ V. Writes O as f16 (EXACT: O = m/8, m <= 788 < 2048) for the
// proj GEMM, and as f32 for the exact f64 fixup path.
__global__ __launch_bounds__(256)
void attn_pv(const float* __restrict__ attn, const u64* __restrict__ vbits,
             ushort* __restrict__ of16, float* __restrict__ of32)
{
    __shared__ ushort Vt[DH][VSTR];
    __shared__ ushort Ss[4][16][VSTR];
    int tb = blockIdx.x, h = blockIdx.y;
    int tid = threadIdx.x, wave = tid >> 6, lane = tid & 63;

    for (int idx = tid; idx < JP*16; idx += 256) {
        int j = idx >> 4, d4 = (idx & 15) << 2;
        ushort vv[4] = {0,0,0,0};
        if (j < N_) {
            u64 vw = vbits[((size_t)tb*N_ + j)*H_ + h];
            #pragma unroll
            for (int r = 0; r < 4; ++r)
                vv[r] = ((vw >> (d4+r)) & 1ull) ? 0x3F80 : 0;
        }
        Vt[d4+0][j]=vv[0]; Vt[d4+1][j]=vv[1]; Vt[d4+2][j]=vv[2]; Vt[d4+3][j]=vv[3];
    }
    for (int idx = lane; idx < 16*16; idx += 64)
        Ss[wave][idx >> 4][208 + (idx & 15)] = 0;
    __syncthreads();

    const int il = lane & 15, kk = (lane >> 4) << 3, ig = (lane >> 4) << 2;
    const size_t amap = ((size_t)tb*H_ + h)*(size_t)(N_*N_);

    for (int it = wave; it < 13; it += 4) {
        int i0 = it << 4;
        #pragma unroll 4
        for (int r = 0; r < 16; ++r) {
            int i = i0 + r;
            bool live = i < N_;
            const float* arow = attn + amap + (size_t)i*N_;
            for (int c = lane; c < NP; c += 64) {
                float av = (live && c < N_) ? arow[c] : 0.f;
                Ss[wave][r][c] = (ushort)(__float_as_uint(av) >> 16);
            }
        }
        #pragma unroll
        for (int dt = 0; dt < 4; ++dt) {
            f32x4 o = {0.f, 0.f, 0.f, 0.f};
            #pragma unroll
            for (int kt = 0; kt < 7; ++kt) {
                short8v a = *(const short8v*)&Ss[wave][il][kt*32 + kk];
                short8v b = *(const short8v*)&Vt[dt*16 + il][kt*32 + kk];
                o = __builtin_amdgcn_mfma_f32_16x16x32_bf16(a, b, o, 0, 0, 0);
            }
            #pragma unroll
            for (int r = 0; r < 4; ++r) {
                int i = i0 + ig + r;
                if (i < N_) {
                    size_t oidx = ((size_t)tb*N_ + i)*D_ + (size_t)h*DH + dt*16 + il;
                    float ov = o[r];
                    of16[oidx] = f16_bits(ov);
                    of32[oidx] = ov;
                }
            }
        }
    }
}

// ---------------------------------------------------------------------------
// Final LIF (proj -> output spikes f32), flag bitmap (no atomics), f64 fixup.
// ---------------------------------------------------------------------------
__global__ void lif_proj(const float* __restrict__ proj, float* __restrict__ outp,
                         u64* __restrict__ flagmap)
{
    int idx = blockIdx.x*256 + threadIdx.x;        // [0, PLANE)
    int lane = threadIdx.x & 63;
    float v = 0.f; bool flag = false;
    #pragma unroll
    for (int t = 0; t < T_; ++t) {
        float xv = proj[(size_t)t*PLANE + idx];
        float h = v + (xv - v)*0.5f;
        bool s = h >= 1.0f;
        flag |= fabsf(h - 1.0f) < FLAG_TOL;
        outp[(size_t)t*PLANE + idx] = s ? 1.0f : 0.0f;
        v = s ? 0.0f : h;
    }
    u64 fm = __ballot(flag);
    if (lane == 0) flagmap[idx >> 6] = fm;
}

__global__ __launch_bounds__(256)
void fixup_proj(const float* __restrict__ of32, const float* __restrict__ Wp,
                const float* __restrict__ bp, float* __restrict__ outp,
                const u64* __restrict__ flagmap)
{
    const int lane = threadIdx.x & 63;
    const int wv = blockIdx.x*4 + (threadIdx.x >> 6);
    const int nw = gridDim.x*4;
    for (int w = wv; w < NFWP; w += nw) {
        u64 fm = flagmap[w];
        while (fm) {
            int bit = __ffsll((long long)fm) - 1;
            fm &= fm - 1;
            int rem = (w << 6) + bit;
            int r = rem >> 9, e = rem & (D_-1);
            const float* wr = Wp + (size_t)e*D_;
            float wv8[8];
            #pragma unroll
            for (int i = 0; i < 8; ++i) wv8[i] = wr[lane + 64*i];
            double dots[T_];
            #pragma unroll
            for (int t = 0; t < T_; ++t) {
                const float* ar = of32 + (size_t)(t*BN_ + r)*D_;
                float av8[8];
                #pragma unroll
                for (int i = 0; i < 8; ++i) av8[i] = ar[lane + 64*i];
                double p = 0.0;
                #pragma unroll
                for (int i = 0; i < 8; ++i) p += (double)av8[i]*(double)wv8[i];
                dots[t] = p;
            }
            #pragma unroll
            for (int off = 32; off > 0; off >>= 1)
                #pragma unroll
                for (int t = 0; t < T_; ++t)
                    dots[t] += __shfl_down(dots[t], off);
            if (lane == 0) {
                double v = 0.0;
                #pragma unroll
                for (int t = 0; t < T_; ++t) {
                    double xt = dots[t] + (double)bp[e];
                    double h = v + (xt - v)/2.0;
                    bool s = h >= 1.0;
                    outp[(size_t)t*PLANE + rem] = s ? 1.0f : 0.0f;
                    v = s ? 0.0 : h;
                }
            }
        }
    }
}

// ---------------------------------------------------------------------------
extern "C" void kernel_launch(void* const* d_in, const int* in_sizes, int n_in,
                              void* d_out, int out_size, void* d_ws, size_t ws_size,
                              hipStream_t stream)
{
    const float* x  = (const float*)d_in[0];
    const float* Wq = (const float*)d_in[1];
    const float* Wk = (const float*)d_in[2];
    const float* Wv = (const float*)d_in[3];
    const float* Wp = (const float*)d_in[4];
    const float* bp = (const float*)d_in[5];
    float* out_spk  = (float*)d_out;                       // (T,B,N,D) spikes
    float* attn_out = (float*)d_out + TENSOR_ELEMS;        // (T,B,H,N,N)

    char* ws = (char*)d_ws;
    const size_t BUFB = (size_t)TENSOR_ELEMS * sizeof(float);   // 25.8 MB
    if (ws_size < 4*BUFB) return;
    // R0: q f32 -> pbuf (proj f32 out)
    float* qkv  = (float*)ws;
    float* pbuf = qkv;
    // R1: k f32 -> O f32 (fixup operand)
    float* of32 = (float*)(ws + 1*BUFB);
    // R2: v f32 -> O f16 (proj GEMM operand)
    ushort* of16 = (ushort*)(ws + 2*BUFB);
    // R3: xh f16 | w3h | wph | bits | flag bitmaps (phases disjoint in time)
    char* r3 = ws + 3*BUFB;
    ushort* xh   = (ushort*)r3;                            // 12.9 MB
    ushort* w3h  = (ushort*)(r3 + (13u<<20));              // 1.5 MB
    ushort* wph  = (ushort*)(r3 + (15u<<20));              // 0.5 MB
    u64*    bits3 = (u64*)(r3 + (16u<<20));                // 2.42 MB
    u64*    qbits = bits3;
    u64*    kbits = bits3 + MH;
    u64*    vbits = bits3 + 2*(size_t)MH;
    u64*    fmap3 = (u64*)(r3 + (19u<<20));                // 605 KB
    u64*    fmapp = (u64*)(r3 + (20u<<20));                // 202 KB

    // f32 -> f16 conversions
    cvt16<<<TENSOR_ELEMS/1024, 256, 0, stream>>>(x, xh, TENSOR_ELEMS);
    cvt16<<<WELEMS/1024, 256, 0, stream>>>(Wq, w3h,            WELEMS);
    cvt16<<<WELEMS/1024, 256, 0, stream>>>(Wk, w3h +   WELEMS, WELEMS);
    cvt16<<<WELEMS/1024, 256, 0, stream>>>(Wv, w3h + 2*WELEMS, WELEMS);
    cvt16<<<WELEMS/1024, 256, 0, stream>>>(Wp, wph,            WELEMS);

    // QKV projections: 1D grid, x-tiles x (y=4 col-blocks x z=3 weights)
    gemm_h<<<99*12, 256, 0, stream>>>(
        xh, w3h, nullptr, qkv, WELEMS, (long)TENSOR_ELEMS, 12, 3);

    // LIF -> packed spike masks + flag bitmap; exact f64 fixup of flagged chains
    lif3_bits<<<3*PLANE/256, 256, 0, stream>>>(qkv, bits3, fmap3);
    fixup_qkv<<<2048, 256, 0, stream>>>(x, Wq, Wk, Wv, bits3, fmap3);

    // attention (exact integer math via bf16 MFMA on 0/1 spikes)
    attn_qk<<<dim3(T_*B_, H_), 256, 0, stream>>>(qbits, kbits, attn_out);
    attn_pv<<<dim3(T_*B_, H_), 256, 0, stream>>>(attn_out, vbits, of16, of32);

    // output projection + bias, LIF + flag bitmap, f64 fixup
    gemm_h<<<99*4, 256, 0, stream>>>(
        of16, wph, bp, pbuf, 0, 0, 4, 1);
    lif_proj<<<PLANE/256, 256, 0, stream>>>(pbuf, out_spk, fmapp);
    fixup_proj<<<1024, 256, 0, stream>>>(of32, Wp, bp, out_spk, fmapp);
}

// Round 8
// 229.603 us; speedup vs baseline: 2.5628x; 1.2166x over previous
//
#include <hip/hip_runtime.h>
#include <stdint.h>

// Problem constants
#define T_ 4
#define B_ 16
#define N_ 197
#define D_ 512
#define H_ 8
#define DH 64
#define BN_ (B_*N_)              // 3152 rows per timestep
#define PLANE (BN_*D_)           // 1,613,824 elems per t-plane
#define M_ (T_*BN_)              // 12608 GEMM rows
#define TENSOR_ELEMS (T_*PLANE)  // 6,455,296 elems per (T,B,N,D) tensor
#define WELEMS (D_*D_)           // 262,144
#define MH (M_*H_)               // 100,864 bitmask words per tensor
#define FLAG_TOL 6e-3f           // ~13 sigma of single-pass f16 dot error
#define NFW3 (3*PLANE/64)        // 75,648 flag words (qkv)
#define NFWP (PLANE/64)          // 25,216 flag words (proj)

typedef __attribute__((ext_vector_type(8))) short short8v;
typedef __attribute__((ext_vector_type(8))) _Float16 f16x8;
typedef __attribute__((ext_vector_type(4))) float f32x4;
typedef __attribute__((ext_vector_type(16))) float f32x16;
typedef __attribute__((ext_vector_type(4))) unsigned short ushort4v;
typedef unsigned long long u64;

__device__ __forceinline__ ushort f16_bits(float f) {
    _Float16 h = (_Float16)f;                      // v_cvt_f16_f32, RNE
    return __builtin_bit_cast(unsigned short, h);
}
__device__ __forceinline__ float f16_val(ushort u) {
    return (float)__builtin_bit_cast(_Float16, u);
}

// async global->LDS 16B copy (one per lane; dest = wave base + lane*16)
__device__ __forceinline__ void gload16(const void* g, void* l) {
    __builtin_amdgcn_global_load_lds(
        (const __attribute__((address_space(1))) unsigned int*)g,
        (__attribute__((address_space(3))) unsigned int*)l, 16, 0, 0);
}

// ---------------------------------------------------------------------------
// f32 -> f16 convert (RNE)
// ---------------------------------------------------------------------------
__global__ void cvt16(const float* __restrict__ src, ushort* __restrict__ dst, int n)
{
    int i = (blockIdx.x*256 + threadIdx.x)*4;
    if (i >= n) return;
    float4 v = *(const float4*)(src + i);
    ushort4v o;
    o[0] = f16_bits(v.x); o[1] = f16_bits(v.y);
    o[2] = f16_bits(v.z); o[3] = f16_bits(v.w);
    *(ushort4v*)(dst + i) = o;
}

// ---------------------------------------------------------------------------
// Single-pass f16 MFMA GEMM: C[M,512] = A[M,512] @ W[512,512]^T (+bias).
// 128x128 tile, BK=64, 4 waves x (64x64), mfma_f32_32x32x16_f16.
// LDS 32KB chunk-planar (conflict-free ds_read_b128 + linear gload_lds dest).
// 1D grid, yz-fastest decode + bijective XCD swizzle.
// ---------------------------------------------------------------------------
__global__ __launch_bounds__(256, 4)
void gemm_h(const ushort* __restrict__ A, const ushort* __restrict__ W,
            const float* __restrict__ bias, float* __restrict__ C,
            int wplane, long cplane, int nyz, int nz)
{
    __shared__ ushort smem[16384];   // 2 planes x [8][128][8] = 32 KB
    const int tid = threadIdx.x;
    const int wave = tid >> 6, lane = tid & 63;
    const int wm = wave >> 1, wn = wave & 1;
    const int l31 = lane & 31, lg = lane >> 5;

    // bijective XCD swizzle (m204), then yz-fastest decode
    int nwg = gridDim.x, orig = blockIdx.x;
    int q8 = nwg >> 3, r8 = nwg & 7, xcd = orig & 7, loc = orig >> 3;
    int wg = (xcd < r8 ? xcd*(q8+1) : r8*(q8+1) + (xcd-r8)*q8) + loc;
    int bx = wg / nyz, yz = wg - bx*nyz;
    int by = yz / nz,  z  = yz - by*nz;

    const int bm0 = bx * 128, bn0 = by * 128;
    const ushort* Wz = W + (size_t)z * wplane;
    float* Cz = C + (size_t)z * cplane;

    f32x16 acc[2][2];
    #pragma unroll
    for (int fi = 0; fi < 2; ++fi)
        #pragma unroll
        for (int fj = 0; fj < 2; ++fj)
            #pragma unroll
            for (int r = 0; r < 16; ++r) acc[fi][fj][r] = 0.f;

    for (int kt = 0; kt < D_; kt += 64) {
        // stage A (128x64 f16 = 16KB) + B (16KB): 8 x 16B chunks per thread
        #pragma unroll
        for (int i = 0; i < 8; ++i) {
            const int q = ((i & 3) << 8) | tid;   // chunk id [0,1024)
            const int row = q & 127, c = q >> 7;  // LDS layout [c][row][8]
            ushort* dst = smem + ((i >> 2) << 13) + q*8;
            if (i < 4) {
                int gr = bm0 + row;
                if (gr < M_) gload16(A + (size_t)gr*D_ + kt + c*8, dst);
            } else {
                int gc = bn0 + row;
                gload16(Wz + (size_t)gc*D_ + kt + c*8, dst);
            }
        }
        __syncthreads();                          // vmcnt drain + barrier
        #pragma unroll
        for (int s = 0; s < 4; ++s) {
            const int cA = (s << 1) | lg;         // chunk: K-slice [cA*8, cA*8+8)
            f16x8 av[2], bv[2];
            #pragma unroll
            for (int f = 0; f < 2; ++f) {
                av[f] = *(const f16x8*)&smem[        (cA*128 + wm*64 + f*32 + l31)*8];
                bv[f] = *(const f16x8*)&smem[8192 + (cA*128 + wn*64 + f*32 + l31)*8];
            }
            #pragma unroll
            for (int fi = 0; fi < 2; ++fi)
                #pragma unroll
                for (int fj = 0; fj < 2; ++fj)
                    acc[fi][fj] = __builtin_amdgcn_mfma_f32_32x32x16_f16(av[fi], bv[fj], acc[fi][fj], 0, 0, 0);
        }
        __syncthreads();                          // protect LDS overwrite
    }
    // epilogue: C/D layout col=lane&31, row=(reg&3)+8*(reg>>2)+4*(lane>>5)
    #pragma unroll
    for (int fi = 0; fi < 2; ++fi)
        #pragma unroll
        for (int fj = 0; fj < 2; ++fj) {
            int gcol = bn0 + wn*64 + fj*32 + l31;
            float bv = bias ? bias[gcol] : 0.f;
            #pragma unroll
            for (int r = 0; r < 16; ++r) {
                int grow = bm0 + wm*64 + fi*32 + (r&3) + 8*(r>>2) + 4*lg;
                if (grow < M_)
                    Cz[(size_t)grow*D_ + gcol] = acc[fi][fj][r] + bv;
            }
        }
}

// ---------------------------------------------------------------------------
// LIF over T=4 for q,k,v -> packed 64-bit spike masks. Flags near-threshold
// chains into a dense per-wave bitmap (NO atomics).
// ---------------------------------------------------------------------------
__global__ void lif3_bits(const float* __restrict__ qkv, u64* __restrict__ bits3,
                          u64* __restrict__ flagmap)
{
    int idx = blockIdx.x*256 + threadIdx.x;        // [0, 3*PLANE)
    int tsr = idx / PLANE;
    int rem = idx - tsr*PLANE;
    const float* buf = qkv + (size_t)tsr*TENSOR_ELEMS;
    u64* bits = bits3 + (size_t)tsr*MH;
    int r = rem >> 9, h = (rem >> 6) & 7;          // wave-uniform
    int lane = threadIdx.x & 63;                   // = d
    float v = 0.f; bool flag = false;
    #pragma unroll
    for (int t = 0; t < T_; ++t) {
        float x = buf[(size_t)t*PLANE + rem];
        float hh = v + (x - v)*0.5f;
        bool s = hh >= 1.0f;
        flag |= fabsf(hh - 1.0f) < FLAG_TOL;
        u64 m = __ballot(s);
        if (lane == 0) bits[(size_t)(t*BN_ + r)*H_ + h] = m;
        v = s ? 0.0f : hh;
    }
    u64 fm = __ballot(flag);
    if (lane == 0) flagmap[idx >> 6] = fm;
}

// ---------------------------------------------------------------------------
// f64 exact recompute of flagged chains (bitmap scan, 4 waves/block, ILP).
// ---------------------------------------------------------------------------
__global__ __launch_bounds__(256)
void fixup_qkv(const float* __restrict__ x,
               const float* __restrict__ Wq, const float* __restrict__ Wk,
               const float* __restrict__ Wv,
               u64* __restrict__ bits3, const u64* __restrict__ flagmap)
{
    const int lane = threadIdx.x & 63;
    const int wv = blockIdx.x*4 + (threadIdx.x >> 6);
    const int nw = gridDim.x*4;
    for (int w = wv; w < NFW3; w += nw) {
        u64 fm = flagmap[w];
        while (fm) {
            int bit = __ffsll((long long)fm) - 1;
            fm &= fm - 1;
            int id = (w << 6) + bit;
            int tsr = id / PLANE;
            int rem = id - tsr*PLANE;
            int r = rem >> 9, e = rem & (D_-1);
            const float* W = (tsr==0) ? Wq : (tsr==1 ? Wk : Wv);
            const float* wr = W + (size_t)e*D_;
            u64* bits = bits3 + (size_t)tsr*MH;
            float wv8[8];
            #pragma unroll
            for (int i = 0; i < 8; ++i) wv8[i] = wr[lane + 64*i];
            double dots[T_];
            #pragma unroll
            for (int t = 0; t < T_; ++t) {
                const float* xr = x + (size_t)(t*BN_ + r)*D_;
                float xv8[8];
                #pragma unroll
                for (int i = 0; i < 8; ++i) xv8[i] = xr[lane + 64*i];
                double p = 0.0;
                #pragma unroll
                for (int i = 0; i < 8; ++i) p += (double)xv8[i]*(double)wv8[i];
                dots[t] = p;
            }
            #pragma unroll
            for (int off = 32; off > 0; off >>= 1)
                #pragma unroll
                for (int t = 0; t < T_; ++t)
                    dots[t] += __shfl_down(dots[t], off);
            if (lane == 0) {
                double v = 0.0;
                u64 b = 1ull << (e & 63);
                #pragma unroll
                for (int t = 0; t < T_; ++t) {
                    double hh = v + (dots[t] - v)/2.0;
                    bool s = hh >= 1.0;
                    size_t wd = (size_t)(t*BN_ + r)*H_ + (e >> 6);
                    if (s) atomicOr(&bits[wd], b);
                    else   atomicAnd(&bits[wd], ~b);
                    v = s ? 0.0 : hh;
                }
            }
        }
    }
}

// ---------------------------------------------------------------------------
// MFMA attention from packed spike masks (exact integer math).
// ---------------------------------------------------------------------------
#define NP 208   // 13 * 16 (padded N)
#define QSTR 72  // LDS row stride (ushorts) for Q/K tiles
#define JP 224   // 7 * 32 (padded j for PV K-dim)
#define VSTR 232 // LDS row stride for Vt

__global__ __launch_bounds__(256)
void attn_qk(const u64* __restrict__ qbits, const u64* __restrict__ kbits,
             float* __restrict__ attn_out)
{
    __shared__ ushort Qs[NP][QSTR];
    __shared__ ushort Ks[NP][QSTR];
    int tb = blockIdx.x, h = blockIdx.y;
    int tid = threadIdx.x, wave = tid >> 6, lane = tid & 63;

    for (int idx = tid; idx < NP*16; idx += 256) {
        int j = idx >> 4, d4 = (idx & 15) << 2;
        ushort qv[4] = {0,0,0,0}, kv[4] = {0,0,0,0};
        if (j < N_) {
            size_t w = ((size_t)tb*N_ + j)*H_ + h;
            u64 qw = qbits[w], kw = kbits[w];
            #pragma unroll
            for (int r = 0; r < 4; ++r) {
                qv[r] = ((qw >> (d4+r)) & 1ull) ? 0x3F80 : 0;
                kv[r] = ((kw >> (d4+r)) & 1ull) ? 0x3F80 : 0;
            }
        }
        #pragma unroll
        for (int r = 0; r < 4; ++r) { Qs[j][d4+r] = qv[r]; Ks[j][d4+r] = kv[r]; }
    }
    __syncthreads();

    const int il = lane & 15;
    const int kk = (lane >> 4) << 3;
    const int ig = (lane >> 4) << 2;
    const size_t amap = ((size_t)tb*H_ + h)*(size_t)(N_*N_);

    for (int it = wave; it < 13; it += 4) {
        int i0 = it << 4;
        short8v a0 = *(const short8v*)&Qs[i0 + il][kk];
        short8v a1 = *(const short8v*)&Qs[i0 + il][kk + 32];
        for (int jt = 0; jt < 13; ++jt) {
            int j0 = jt << 4;
            short8v b0 = *(const short8v*)&Ks[j0 + il][kk];
            short8v b1 = *(const short8v*)&Ks[j0 + il][kk + 32];
            f32x4 c = {0.f, 0.f, 0.f, 0.f};
            c = __builtin_amdgcn_mfma_f32_16x16x32_bf16(a0, b0, c, 0, 0, 0);
            c = __builtin_amdgcn_mfma_f32_16x16x32_bf16(a1, b1, c, 0, 0, 0);
            int j = j0 + il;
            if (j < N_) {
                #pragma unroll
                for (int r = 0; r < 4; ++r) {
                    int i = i0 + ig + r;
                    if (i < N_) attn_out[amap + (size_t)i*N_ + j] = c[r]*0.125f;
                }
            }
        }
    }
}

// O = attn @ V. A-fragments read DIRECTLY from global S (L3-resident, written
// by attn_qk) -> no Ss staging, Vt-only LDS. Writes O as f16 only (EXACT:
// O = m/8 with m <= 788 < 2^11). Dead rows (>=N_) are clamped in-bounds;
// their garbage only feeds C-rows >= N_ (discarded) since V cols >= N_ are 0.
__global__ __launch_bounds__(256)
void attn_pv(const float* __restrict__ attn, const u64* __restrict__ vbits,
             ushort* __restrict__ of16)
{
    __shared__ ushort Vt[DH][VSTR];
    int tb = blockIdx.x, h = blockIdx.y, zh = blockIdx.z;
    int tid = threadIdx.x, wave = tid >> 6, lane = tid & 63;

    // stage V transposed: Vt[d][j], j >= N_ zeroed
    for (int idx = tid; idx < JP*16; idx += 256) {
        int j = idx >> 4, d4 = (idx & 15) << 2;
        ushort vv[4] = {0,0,0,0};
        if (j < N_) {
            u64 vw = vbits[((size_t)tb*N_ + j)*H_ + h];
            #pragma unroll
            for (int r = 0; r < 4; ++r)
                vv[r] = ((vw >> (d4+r)) & 1ull) ? 0x3F80 : 0;
        }
        Vt[d4+0][j]=vv[0]; Vt[d4+1][j]=vv[1]; Vt[d4+2][j]=vv[2]; Vt[d4+3][j]=vv[3];
    }
    __syncthreads();

    const int il = lane & 15, kk = (lane >> 4) << 3, ig = (lane >> 4) << 2;
    const size_t amap = ((size_t)tb*H_ + h)*(size_t)(N_*N_);

    const int it_lo = zh*7 + wave;                 // z=0: strips 0..6, z=1: 7..12
    const int it_hi = zh*7 + 7 < 13 ? zh*7 + 7 : 13;
    for (int it = it_lo; it < it_hi; it += 4) {
        int i0 = it << 4;
        int row = i0 + il; if (row > N_-1) row = N_-1;     // clamp (in-bounds)
        const float* arow = attn + amap + (size_t)row*N_;
        f32x4 o[4];
        #pragma unroll
        for (int dt = 0; dt < 4; ++dt) o[dt] = (f32x4){0.f,0.f,0.f,0.f};
        #pragma unroll
        for (int kt = 0; kt < 7; ++kt) {
            const int c0 = kt*32 + kk;
            float f[8];
            if (kt < 6) {
                float4 fa = *(const float4*)(arow + c0);
                float4 fb = *(const float4*)(arow + c0 + 4);
                f[0]=fa.x; f[1]=fa.y; f[2]=fa.z; f[3]=fa.w;
                f[4]=fb.x; f[5]=fb.y; f[6]=fb.z; f[7]=fb.w;
            } else {
                #pragma unroll
                for (int j = 0; j < 8; ++j)
                    f[j] = (c0 + j < N_) ? arow[c0 + j] : 0.f;
            }
            short8v a;
            #pragma unroll
            for (int j = 0; j < 8; ++j)
                a[j] = (short)(__float_as_uint(f[j]) >> 16);   // exact: S=k/8, k<256
            #pragma unroll
            for (int dt = 0; dt < 4; ++dt) {
                short8v b = *(const short8v*)&Vt[dt*16 + il][c0];
                o[dt] = __builtin_amdgcn_mfma_f32_16x16x32_bf16(a, b, o[dt], 0, 0, 0);
            }
        }
        #pragma unroll
        for (int dt = 0; dt < 4; ++dt)
            #pragma unroll
            for (int r = 0; r < 4; ++r) {
                int i = i0 + ig + r;
                if (i < N_)
                    of16[((size_t)tb*N_ + i)*D_ + (size_t)h*DH + dt*16 + il] =
                        f16_bits(o[dt][r]);
            }
    }
}

// ---------------------------------------------------------------------------
// Final LIF (proj -> output spikes f32), flag bitmap (no atomics), f64 fixup.
// ---------------------------------------------------------------------------
__global__ void lif_proj(const float* __restrict__ proj, float* __restrict__ outp,
                         u64* __restrict__ flagmap)
{
    int idx = blockIdx.x*256 + threadIdx.x;        // [0, PLANE)
    int lane = threadIdx.x & 63;
    float v = 0.f; bool flag = false;
    #pragma unroll
    for (int t = 0; t < T_; ++t) {
        float xv = proj[(size_t)t*PLANE + idx];
        float h = v + (xv - v)*0.5f;
        bool s = h >= 1.0f;
        flag |= fabsf(h - 1.0f) < FLAG_TOL;
        outp[(size_t)t*PLANE + idx] = s ? 1.0f : 0.0f;
        v = s ? 0.0f : h;
    }
    u64 fm = __ballot(flag);
    if (lane == 0) flagmap[idx >> 6] = fm;
}

// Reads O from of16 (exact: O = m/8, m <= 788 -> f16 lossless).
__global__ __launch_bounds__(256)
void fixup_proj(const ushort* __restrict__ of16, const float* __restrict__ Wp,
                const float* __restrict__ bp, float* __restrict__ outp,
                const u64* __restrict__ flagmap)
{
    const int lane = threadIdx.x & 63;
    const int wv = blockIdx.x*4 + (threadIdx.x >> 6);
    const int nw = gridDim.x*4;
    for (int w = wv; w < NFWP; w += nw) {
        u64 fm = flagmap[w];
        while (fm) {
            int bit = __ffsll((long long)fm) - 1;
            fm &= fm - 1;
            int rem = (w << 6) + bit;
            int r = rem >> 9, e = rem & (D_-1);
            const float* wr = Wp + (size_t)e*D_;
            float wv8[8];
            #pragma unroll
            for (int i = 0; i < 8; ++i) wv8[i] = wr[lane + 64*i];
            double dots[T_];
            #pragma unroll
            for (int t = 0; t < T_; ++t) {
                const ushort* ar = of16 + (size_t)(t*BN_ + r)*D_;
                float av8[8];
                #pragma unroll
                for (int i = 0; i < 8; ++i) av8[i] = f16_val(ar[lane + 64*i]);
                double p = 0.0;
                #pragma unroll
                for (int i = 0; i < 8; ++i) p += (double)av8[i]*(double)wv8[i];
                dots[t] = p;
            }
            #pragma unroll
            for (int off = 32; off > 0; off >>= 1)
                #pragma unroll
                for (int t = 0; t < T_; ++t)
                    dots[t] += __shfl_down(dots[t], off);
            if (lane == 0) {
                double v = 0.0;
                #pragma unroll
                for (int t = 0; t < T_; ++t) {
                    double xt = dots[t] + (double)bp[e];
                    double h = v + (xt - v)/2.0;
                    bool s = h >= 1.0;
                    outp[(size_t)t*PLANE + rem] = s ? 1.0f : 0.0f;
                    v = s ? 0.0 : h;
                }
            }
        }
    }
}

// ---------------------------------------------------------------------------
extern "C" void kernel_launch(void* const* d_in, const int* in_sizes, int n_in,
                              void* d_out, int out_size, void* d_ws, size_t ws_size,
                              hipStream_t stream)
{
    const float* x  = (const float*)d_in[0];
    const float* Wq = (const float*)d_in[1];
    const float* Wk = (const float*)d_in[2];
    const float* Wv = (const float*)d_in[3];
    const float* Wp = (const float*)d_in[4];
    const float* bp = (const float*)d_in[5];
    float* out_spk  = (float*)d_out;                       // (T,B,N,D) spikes
    float* attn_out = (float*)d_out + TENSOR_ELEMS;        // (T,B,H,N,N)

    char* ws = (char*)d_ws;
    const size_t BUFB = (size_t)TENSOR_ELEMS * sizeof(float);   // 25.8 MB
    if (ws_size < 4*BUFB) return;
    // R0: q f32 -> pbuf (proj f32 out)
    float* qkv  = (float*)ws;
    float* pbuf = qkv;
    // R2: v f32 -> O f16 (proj GEMM + fixup operand; exact)
    ushort* of16 = (ushort*)(ws + 2*BUFB);
    // R3: xh f16 | w3h | wph | bits | flag bitmaps (phases disjoint in time)
    char* r3 = ws + 3*BUFB;
    ushort* xh   = (ushort*)r3;                            // 12.9 MB
    ushort* w3h  = (ushort*)(r3 + (13u<<20));              // 1.5 MB
    ushort* wph  = (ushort*)(r3 + (15u<<20));              // 0.5 MB
    u64*    bits3 = (u64*)(r3 + (16u<<20));                // 2.42 MB
    u64*    qbits = bits3;
    u64*    kbits = bits3 + MH;
    u64*    vbits = bits3 + 2*(size_t)MH;
    u64*    fmap3 = (u64*)(r3 + (19u<<20));                // 605 KB
    u64*    fmapp = (u64*)(r3 + (20u<<20));                // 202 KB

    // f32 -> f16 conversions
    cvt16<<<TENSOR_ELEMS/1024, 256, 0, stream>>>(x, xh, TENSOR_ELEMS);
    cvt16<<<WELEMS/1024, 256, 0, stream>>>(Wq, w3h,            WELEMS);
    cvt16<<<WELEMS/1024, 256, 0, stream>>>(Wk, w3h +   WELEMS, WELEMS);
    cvt16<<<WELEMS/1024, 256, 0, stream>>>(Wv, w3h + 2*WELEMS, WELEMS);
    cvt16<<<WELEMS/1024, 256, 0, stream>>>(Wp, wph,            WELEMS);

    // QKV projections: 1D grid, x-tiles x (y=4 col-blocks x z=3 weights)
    gemm_h<<<99*12, 256, 0, stream>>>(
        xh, w3h, nullptr, qkv, WELEMS, (long)TENSOR_ELEMS, 12, 3);

    // LIF -> packed spike masks + flag bitmap; exact f64 fixup of flagged chains
    lif3_bits<<<3*PLANE/256, 256, 0, stream>>>(qkv, bits3, fmap3);
    fixup_qkv<<<2048, 256, 0, stream>>>(x, Wq, Wk, Wv, bits3, fmap3);

    // attention (exact integer math via bf16 MFMA on 0/1 spikes)
    attn_qk<<<dim3(T_*B_, H_), 256, 0, stream>>>(qbits, kbits, attn_out);
    attn_pv<<<dim3(T_*B_, H_, 2), 256, 0, stream>>>(attn_out, vbits, of16);

    // output projection + bias, LIF + flag bitmap, f64 fixup
    gemm_h<<<99*4, 256, 0, stream>>>(
        of16, wph, bp, pbuf, 0, 0, 4, 1);
    lif_proj<<<PLANE/256, 256, 0, stream>>>(pbuf, out_spk, fmapp);
    fixup_proj<<<1024, 256, 0, stream>>>(of16, Wp, bp, out_spk, fmapp);
}

// Round 9
// 181.497 us; speedup vs baseline: 3.2421x; 1.2651x over previous
//
#include <hip/hip_runtime.h>
#include <stdint.h>

// Problem constants
#define T_ 4
#define B_ 16
#define N_ 197
#define D_ 512
#define H_ 8
#define DH 64
#define BN_ (B_*N_)              // 3152 rows per timestep
#define PLANE (BN_*D_)           // 1,613,824 elems per t-plane
#define M_ (T_*BN_)              // 12608 GEMM rows
#define TENSOR_ELEMS (T_*PLANE)  // 6,455,296 elems per (T,B,N,D) tensor
#define WELEMS (D_*D_)           // 262,144
#define MH (M_*H_)               // 100,864 bitmask words per tensor
#define FLAG_TOL 6e-3f           // ~13 sigma of single-pass f16 dot error
#define NFW3 (3*PLANE/64)        // 75,648 flag words (qkv)
#define NFWP (PLANE/64)          // 25,216 flag words (proj / per tensor)

typedef __attribute__((ext_vector_type(8))) short short8v;
typedef __attribute__((ext_vector_type(8))) _Float16 f16x8;
typedef __attribute__((ext_vector_type(4))) float f32x4;
typedef __attribute__((ext_vector_type(16))) float f32x16;
typedef __attribute__((ext_vector_type(4))) unsigned short ushort4v;
typedef unsigned long long u64;
typedef unsigned int u32;

__device__ __forceinline__ ushort f16_bits(float f) {
    _Float16 h = (_Float16)f;                      // v_cvt_f16_f32, RNE
    return __builtin_bit_cast(unsigned short, h);
}
__device__ __forceinline__ float f16_val(ushort u) {
    return (float)__builtin_bit_cast(_Float16, u);
}

// async global->LDS 16B copy (one per lane; dest = wave base + lane*16)
__device__ __forceinline__ void gload16(const void* g, void* l) {
    __builtin_amdgcn_global_load_lds(
        (const __attribute__((address_space(1))) unsigned int*)g,
        (__attribute__((address_space(3))) unsigned int*)l, 16, 0, 0);
}

// ---------------------------------------------------------------------------
// f32 -> f16 convert (RNE)
// ---------------------------------------------------------------------------
__global__ void cvt16(const float* __restrict__ src, ushort* __restrict__ dst, int n)
{
    int i = (blockIdx.x*256 + threadIdx.x)*4;
    if (i >= n) return;
    float4 v = *(const float4*)(src + i);
    ushort4v o;
    o[0] = f16_bits(v.x); o[1] = f16_bits(v.y);
    o[2] = f16_bits(v.z); o[3] = f16_bits(v.w);
    *(ushort4v*)(dst + i) = o;
}

// ---------------------------------------------------------------------------
// Fused f16 GEMM + LIF + spike-bit pack (QKV). Tile: 32 BN-rows x 128 cols
// x ALL 4 timesteps (A-tile = 4 t-planes x 32 rows = 128 LDS rows). Per wave:
// 32 cols (wn), acc[4 t]. LIF chain in-register over t; spike/flag words
// assembled via ballot halves in LDS -> bits3/fmap3 written whole (no atomics).
// No f32 C output at all.
// ---------------------------------------------------------------------------
__global__ __launch_bounds__(256, 4)
void gemm_qkv_lif(const ushort* __restrict__ xh, const ushort* __restrict__ w3h,
                  u64* __restrict__ bits3, u64* __restrict__ fmap3)
{
    __shared__ __align__(16) ushort smem[16384];   // A 16KB | B 16KB
    const int tid = threadIdx.x;
    const int lane = tid & 63, wn = tid >> 6;      // wave owns 32 cols
    const int l31 = lane & 31, lg = lane >> 5;
    const int nyz = 12, nz = 3;

    // bijective XCD swizzle + yz-fastest decode
    int nwg = gridDim.x, orig = blockIdx.x;
    int q8 = nwg >> 3, r8 = nwg & 7, xcd = orig & 7, loc = orig >> 3;
    int wg = (xcd < r8 ? xcd*(q8+1) : r8*(q8+1) + (xcd-r8)*q8) + loc;
    int bx = wg / nyz, yz = wg - bx*nyz;
    int by = yz / nz,  z  = yz - by*nz;

    const int bm0 = bx * 32;                       // row offset within BN_
    const int bn0 = by * 128;
    const ushort* Wz = w3h + (size_t)z * WELEMS;

    f32x16 acc[4];
    #pragma unroll
    for (int t = 0; t < 4; ++t)
        #pragma unroll
        for (int r = 0; r < 16; ++r) acc[t][r] = 0.f;

    for (int kt = 0; kt < D_; kt += 64) {
        #pragma unroll
        for (int i = 0; i < 8; ++i) {
            const int q = ((i & 3) << 8) | tid;    // chunk id [0,1024)
            const int row = q & 127, c = q >> 7;   // LDS [c][row128][8]
            ushort* dst = smem + ((i >> 2) << 13) + q*8;
            if (i < 4) {
                int t = row >> 5, r32 = row & 31;
                if (bm0 + r32 < BN_)
                    gload16(xh + ((size_t)(t*BN_ + bm0 + r32)*D_ + kt + c*8), dst);
            } else {
                gload16(Wz + ((size_t)(bn0 + row)*D_ + kt + c*8), dst);
            }
        }
        __syncthreads();
        #pragma unroll
        for (int s = 0; s < 4; ++s) {
            const int cA = (s << 1) | lg;
            f16x8 bv = *(const f16x8*)&smem[8192 + (cA*128 + wn*32 + l31)*8];
            #pragma unroll
            for (int t = 0; t < 4; ++t) {
                f16x8 av = *(const f16x8*)&smem[(cA*128 + t*32 + l31)*8];
                acc[t] = __builtin_amdgcn_mfma_f32_32x32x16_f16(av, bv, acc[t], 0, 0, 0);
            }
        }
        __syncthreads();
    }

    // ---- fused LIF epilogue ----
    // acc[t][r]: row32 = (r&3)+8*(r>>2)+4*lg, col = bn0 + wn*32 + l31
    u32* sp = (u32*)smem;          // [wn][t][r][lg] spike halves (512 u32)
    u32* fl = (u32*)smem + 512;    // [wn][r][lg] flag halves (128 u32)
    #pragma unroll
    for (int r = 0; r < 16; ++r) {
        bool s[4]; bool fg = false; float v = 0.f;
        #pragma unroll
        for (int t = 0; t < 4; ++t) {
            float h = v + (acc[t][r] - v)*0.5f;
            s[t] = h >= 1.0f;
            fg |= fabsf(h - 1.0f) < FLAG_TOL;
            v = s[t] ? 0.f : h;
        }
        #pragma unroll
        for (int t = 0; t < 4; ++t) {
            u64 m = __ballot(s[t]);
            if (lane == 0) {
                sp[((wn*4 + t)*16 + r)*2 + 0] = (u32)m;
                sp[((wn*4 + t)*16 + r)*2 + 1] = (u32)(m >> 32);
            }
        }
        u64 fm = __ballot(fg);
        if (lane == 0) {
            fl[(wn*16 + r)*2 + 0] = (u32)fm;
            fl[(wn*16 + r)*2 + 1] = (u32)(fm >> 32);
        }
    }
    __syncthreads();
    // assemble + store: word(h_local) = low32 from wn=2h, high32 from wn=2h+1
    {
        int t = tid >> 6, row32 = (tid >> 1) & 31, hl = tid & 1;
        int rr = (row32 & 3) | ((row32 >> 3) << 2);
        int lgg = (row32 >> 2) & 1;
        u64 word = (u64)sp[(((2*hl)*4 + t)*16 + rr)*2 + lgg]
                 | ((u64)sp[(((2*hl+1)*4 + t)*16 + rr)*2 + lgg] << 32);
        if (bm0 + row32 < BN_)
            bits3[(size_t)z*MH + (size_t)(t*BN_ + bm0 + row32)*H_ + (bn0 >> 6) + hl] = word;
        if (tid < 64) {
            int rowf = tid >> 1, hlf = tid & 1;
            int rf = (rowf & 3) | ((rowf >> 3) << 2);
            int lgf = (rowf >> 2) & 1;
            u64 fw = (u64)fl[((2*hlf)*16 + rf)*2 + lgf]
                   | ((u64)fl[((2*hlf+1)*16 + rf)*2 + lgf] << 32);
            if (bm0 + rowf < BN_)
                fmap3[(size_t)z*NFWP + (size_t)(bm0 + rowf)*8 + (bn0 >> 6) + hlf] = fw;
        }
    }
}

// ---------------------------------------------------------------------------
// Fused f16 GEMM + bias + LIF (proj). Same tiling; writes out_spk f32 0/1
// directly + flag bitmap. No pbuf intermediate.
// ---------------------------------------------------------------------------
__global__ __launch_bounds__(256, 4)
void gemm_proj_lif(const ushort* __restrict__ oh, const ushort* __restrict__ wph,
                   const float* __restrict__ bias, float* __restrict__ outp,
                   u64* __restrict__ fmapp)
{
    __shared__ __align__(16) ushort smem[16384];
    const int tid = threadIdx.x;
    const int lane = tid & 63, wn = tid >> 6;
    const int l31 = lane & 31, lg = lane >> 5;
    const int nyz = 4;

    int nwg = gridDim.x, orig = blockIdx.x;
    int q8 = nwg >> 3, r8 = nwg & 7, xcd = orig & 7, loc = orig >> 3;
    int wg = (xcd < r8 ? xcd*(q8+1) : r8*(q8+1) + (xcd-r8)*q8) + loc;
    int bx = wg / nyz, by = wg - bx*nyz;

    const int bm0 = bx * 32, bn0 = by * 128;

    f32x16 acc[4];
    #pragma unroll
    for (int t = 0; t < 4; ++t)
        #pragma unroll
        for (int r = 0; r < 16; ++r) acc[t][r] = 0.f;

    for (int kt = 0; kt < D_; kt += 64) {
        #pragma unroll
        for (int i = 0; i < 8; ++i) {
            const int q = ((i & 3) << 8) | tid;
            const int row = q & 127, c = q >> 7;
            ushort* dst = smem + ((i >> 2) << 13) + q*8;
            if (i < 4) {
                int t = row >> 5, r32 = row & 31;
                if (bm0 + r32 < BN_)
                    gload16(oh + ((size_t)(t*BN_ + bm0 + r32)*D_ + kt + c*8), dst);
            } else {
                gload16(wph + ((size_t)(bn0 + row)*D_ + kt + c*8), dst);
            }
        }
        __syncthreads();
        #pragma unroll
        for (int s = 0; s < 4; ++s) {
            const int cA = (s << 1) | lg;
            f16x8 bv = *(const f16x8*)&smem[8192 + (cA*128 + wn*32 + l31)*8];
            #pragma unroll
            for (int t = 0; t < 4; ++t) {
                f16x8 av = *(const f16x8*)&smem[(cA*128 + t*32 + l31)*8];
                acc[t] = __builtin_amdgcn_mfma_f32_32x32x16_f16(av, bv, acc[t], 0, 0, 0);
            }
        }
        __syncthreads();
    }

    const int gcol = bn0 + wn*32 + l31;
    const float bb = bias[gcol];
    u32* fl = (u32*)smem;          // [wn][r][lg] flag halves
    #pragma unroll
    for (int r = 0; r < 16; ++r) {
        const int row32 = (r & 3) + 8*(r >> 2) + 4*lg;
        const bool live = bm0 + row32 < BN_;
        bool fg = false; float v = 0.f;
        #pragma unroll
        for (int t = 0; t < 4; ++t) {
            float h = v + ((acc[t][r] + bb) - v)*0.5f;
            bool st = h >= 1.0f;
            fg |= fabsf(h - 1.0f) < FLAG_TOL;
            if (live)
                outp[(size_t)t*PLANE + (size_t)(bm0 + row32)*D_ + gcol] = st ? 1.0f : 0.0f;
            v = st ? 0.f : h;
        }
        u64 fm = __ballot(fg);
        if (lane == 0) {
            fl[(wn*16 + r)*2 + 0] = (u32)fm;
            fl[(wn*16 + r)*2 + 1] = (u32)(fm >> 32);
        }
    }
    __syncthreads();
    if (tid < 64) {
        int rowf = tid >> 1, hlf = tid & 1;
        int rf = (rowf & 3) | ((rowf >> 3) << 2);
        int lgf = (rowf >> 2) & 1;
        u64 fw = (u64)fl[((2*hlf)*16 + rf)*2 + lgf]
               | ((u64)fl[((2*hlf+1)*16 + rf)*2 + lgf] << 32);
        if (bm0 + rowf < BN_)
            fmapp[(size_t)(bm0 + rowf)*8 + (bn0 >> 6) + hlf] = fw;
    }
}

// ---------------------------------------------------------------------------
// f64 exact recompute of flagged chains (bitmap scan, 4 waves/block, ILP).
// ---------------------------------------------------------------------------
__global__ __launch_bounds__(256)
void fixup_qkv(const float* __restrict__ x,
               const float* __restrict__ Wq, const float* __restrict__ Wk,
               const float* __restrict__ Wv,
               u64* __restrict__ bits3, const u64* __restrict__ flagmap)
{
    const int lane = threadIdx.x & 63;
    const int wv = blockIdx.x*4 + (threadIdx.x >> 6);
    const int nw = gridDim.x*4;
    for (int w = wv; w < NFW3; w += nw) {
        u64 fm = flagmap[w];
        while (fm) {
            int bit = __ffsll((long long)fm) - 1;
            fm &= fm - 1;
            int id = (w << 6) + bit;
            int tsr = id / PLANE;
            int rem = id - tsr*PLANE;
            int r = rem >> 9, e = rem & (D_-1);
            const float* W = (tsr==0) ? Wq : (tsr==1 ? Wk : Wv);
            const float* wr = W + (size_t)e*D_;
            u64* bits = bits3 + (size_t)tsr*MH;
            float wv8[8];
            #pragma unroll
            for (int i = 0; i < 8; ++i) wv8[i] = wr[lane + 64*i];
            double dots[T_];
            #pragma unroll
            for (int t = 0; t < T_; ++t) {
                const float* xr = x + (size_t)(t*BN_ + r)*D_;
                float xv8[8];
                #pragma unroll
                for (int i = 0; i < 8; ++i) xv8[i] = xr[lane + 64*i];
                double p = 0.0;
                #pragma unroll
                for (int i = 0; i < 8; ++i) p += (double)xv8[i]*(double)wv8[i];
                dots[t] = p;
            }
            #pragma unroll
            for (int off = 32; off > 0; off >>= 1)
                #pragma unroll
                for (int t = 0; t < T_; ++t)
                    dots[t] += __shfl_down(dots[t], off);
            if (lane == 0) {
                double v = 0.0;
                u64 b = 1ull << (e & 63);
                #pragma unroll
                for (int t = 0; t < T_; ++t) {
                    double hh = v + (dots[t] - v)/2.0;
                    bool s = hh >= 1.0;
                    size_t wd = (size_t)(t*BN_ + r)*H_ + (e >> 6);
                    if (s) atomicOr(&bits[wd], b);
                    else   atomicAnd(&bits[wd], ~b);
                    v = s ? 0.0 : hh;
                }
            }
        }
    }
}

// ---------------------------------------------------------------------------
// MFMA attention from packed spike masks (exact integer math).
// ---------------------------------------------------------------------------
#define NP 208   // 13 * 16 (padded N)
#define QSTR 72  // LDS row stride (ushorts) for Q/K tiles
#define JP 224   // 7 * 32 (padded j for PV K-dim)
#define VSTR 232 // LDS row stride for Vt

__global__ __launch_bounds__(256)
void attn_qk(const u64* __restrict__ qbits, const u64* __restrict__ kbits,
             float* __restrict__ attn_out)
{
    __shared__ ushort Qs[NP][QSTR];
    __shared__ ushort Ks[NP][QSTR];
    int tb = blockIdx.x, h = blockIdx.y;
    int tid = threadIdx.x, wave = tid >> 6, lane = tid & 63;

    for (int idx = tid; idx < NP*16; idx += 256) {
        int j = idx >> 4, d4 = (idx & 15) << 2;
        ushort qv[4] = {0,0,0,0}, kv[4] = {0,0,0,0};
        if (j < N_) {
            size_t w = ((size_t)tb*N_ + j)*H_ + h;
            u64 qw = qbits[w], kw = kbits[w];
            #pragma unroll
            for (int r = 0; r < 4; ++r) {
                qv[r] = ((qw >> (d4+r)) & 1ull) ? 0x3F80 : 0;
                kv[r] = ((kw >> (d4+r)) & 1ull) ? 0x3F80 : 0;
            }
        }
        #pragma unroll
        for (int r = 0; r < 4; ++r) { Qs[j][d4+r] = qv[r]; Ks[j][d4+r] = kv[r]; }
    }
    __syncthreads();

    const int il = lane & 15;
    const int kk = (lane >> 4) << 3;
    const int ig = (lane >> 4) << 2;
    const size_t amap = ((size_t)tb*H_ + h)*(size_t)(N_*N_);

    for (int it = wave; it < 13; it += 4) {
        int i0 = it << 4;
        short8v a0 = *(const short8v*)&Qs[i0 + il][kk];
        short8v a1 = *(const short8v*)&Qs[i0 + il][kk + 32];
        for (int jt = 0; jt < 13; ++jt) {
            int j0 = jt << 4;
            short8v b0 = *(const short8v*)&Ks[j0 + il][kk];
            short8v b1 = *(const short8v*)&Ks[j0 + il][kk + 32];
            f32x4 c = {0.f, 0.f, 0.f, 0.f};
            c = __builtin_amdgcn_mfma_f32_16x16x32_bf16(a0, b0, c, 0, 0, 0);
            c = __builtin_amdgcn_mfma_f32_16x16x32_bf16(a1, b1, c, 0, 0, 0);
            int j = j0 + il;
            if (j < N_) {
                #pragma unroll
                for (int r = 0; r < 4; ++r) {
                    int i = i0 + ig + r;
                    if (i < N_) attn_out[amap + (size_t)i*N_ + j] = c[r]*0.125f;
                }
            }
        }
    }
}

// O = attn @ V. A-fragments read directly from global S (L3-resident).
// Writes O as f16 only (EXACT: O = m/8, m <= 788 < 2^11).
__global__ __launch_bounds__(256)
void attn_pv(const float* __restrict__ attn, const u64* __restrict__ vbits,
             ushort* __restrict__ of16)
{
    __shared__ ushort Vt[DH][VSTR];
    int tb = blockIdx.x, h = blockIdx.y, zh = blockIdx.z;
    int tid = threadIdx.x, wave = tid >> 6, lane = tid & 63;

    for (int idx = tid; idx < JP*16; idx += 256) {
        int j = idx >> 4, d4 = (idx & 15) << 2;
        ushort vv[4] = {0,0,0,0};
        if (j < N_) {
            u64 vw = vbits[((size_t)tb*N_ + j)*H_ + h];
            #pragma unroll
            for (int r = 0; r < 4; ++r)
                vv[r] = ((vw >> (d4+r)) & 1ull) ? 0x3F80 : 0;
        }
        Vt[d4+0][j]=vv[0]; Vt[d4+1][j]=vv[1]; Vt[d4+2][j]=vv[2]; Vt[d4+3][j]=vv[3];
    }
    __syncthreads();

    const int il = lane & 15, kk = (lane >> 4) << 3, ig = (lane >> 4) << 2;
    const size_t amap = ((size_t)tb*H_ + h)*(size_t)(N_*N_);

    const int it_lo = zh*7 + wave;
    const int it_hi = zh*7 + 7 < 13 ? zh*7 + 7 : 13;
    for (int it = it_lo; it < it_hi; it += 4) {
        int i0 = it << 4;
        int row = i0 + il; if (row > N_-1) row = N_-1;
        const float* arow = attn + amap + (size_t)row*N_;
        f32x4 o[4];
        #pragma unroll
        for (int dt = 0; dt < 4; ++dt) o[dt] = (f32x4){0.f,0.f,0.f,0.f};
        #pragma unroll
        for (int kt = 0; kt < 7; ++kt) {
            const int c0 = kt*32 + kk;
            float f[8];
            if (kt < 6) {
                float4 fa = *(const float4*)(arow + c0);
                float4 fb = *(const float4*)(arow + c0 + 4);
                f[0]=fa.x; f[1]=fa.y; f[2]=fa.z; f[3]=fa.w;
                f[4]=fb.x; f[5]=fb.y; f[6]=fb.z; f[7]=fb.w;
            } else {
                #pragma unroll
                for (int j = 0; j < 8; ++j)
                    f[j] = (c0 + j < N_) ? arow[c0 + j] : 0.f;
            }
            short8v a;
            #pragma unroll
            for (int j = 0; j < 8; ++j)
                a[j] = (short)(__float_as_uint(f[j]) >> 16);
            #pragma unroll
            for (int dt = 0; dt < 4; ++dt) {
                short8v b = *(const short8v*)&Vt[dt*16 + il][c0];
                o[dt] = __builtin_amdgcn_mfma_f32_16x16x32_bf16(a, b, o[dt], 0, 0, 0);
            }
        }
        #pragma unroll
        for (int dt = 0; dt < 4; ++dt)
            #pragma unroll
            for (int r = 0; r < 4; ++r) {
                int i = i0 + ig + r;
                if (i < N_)
                    of16[((size_t)tb*N_ + i)*D_ + (size_t)h*DH + dt*16 + il] =
                        f16_bits(o[dt][r]);
            }
    }
}

// ---------------------------------------------------------------------------
// fixup_proj: exact f64 recompute of flagged proj chains (reads of16, exact).
// ---------------------------------------------------------------------------
__global__ __launch_bounds__(256)
void fixup_proj(const ushort* __restrict__ of16, const float* __restrict__ Wp,
                const float* __restrict__ bp, float* __restrict__ outp,
                const u64* __restrict__ flagmap)
{
    const int lane = threadIdx.x & 63;
    const int wv = blockIdx.x*4 + (threadIdx.x >> 6);
    const int nw = gridDim.x*4;
    for (int w = wv; w < NFWP; w += nw) {
        u64 fm = flagmap[w];
        while (fm) {
            int bit = __ffsll((long long)fm) - 1;
            fm &= fm - 1;
            int rem = (w << 6) + bit;
            int r = rem >> 9, e = rem & (D_-1);
            const float* wr = Wp + (size_t)e*D_;
            float wv8[8];
            #pragma unroll
            for (int i = 0; i < 8; ++i) wv8[i] = wr[lane + 64*i];
            double dots[T_];
            #pragma unroll
            for (int t = 0; t < T_; ++t) {
                const ushort* ar = of16 + (size_t)(t*BN_ + r)*D_;
                float av8[8];
                #pragma unroll
                for (int i = 0; i < 8; ++i) av8[i] = f16_val(ar[lane + 64*i]);
                double p = 0.0;
                #pragma unroll
                for (int i = 0; i < 8; ++i) p += (double)av8[i]*(double)wv8[i];
                dots[t] = p;
            }
            #pragma unroll
            for (int off = 32; off > 0; off >>= 1)
                #pragma unroll
                for (int t = 0; t < T_; ++t)
                    dots[t] += __shfl_down(dots[t], off);
            if (lane == 0) {
                double v = 0.0;
                #pragma unroll
                for (int t = 0; t < T_; ++t) {
                    double xt = dots[t] + (double)bp[e];
                    double h = v + (xt - v)/2.0;
                    bool s = h >= 1.0;
                    outp[(size_t)t*PLANE + rem] = s ? 1.0f : 0.0f;
                    v = s ? 0.0 : h;
                }
            }
        }
    }
}

// ---------------------------------------------------------------------------
extern "C" void kernel_launch(void* const* d_in, const int* in_sizes, int n_in,
                              void* d_out, int out_size, void* d_ws, size_t ws_size,
                              hipStream_t stream)
{
    const float* x  = (const float*)d_in[0];
    const float* Wq = (const float*)d_in[1];
    const float* Wk = (const float*)d_in[2];
    const float* Wv = (const float*)d_in[3];
    const float* Wp = (const float*)d_in[4];
    const float* bp = (const float*)d_in[5];
    float* out_spk  = (float*)d_out;                       // (T,B,N,D) spikes
    float* attn_out = (float*)d_out + TENSOR_ELEMS;        // (T,B,H,N,N)

    char* ws = (char*)d_ws;
    const size_t BUFB = (size_t)TENSOR_ELEMS * sizeof(float);   // 25.8 MB
    if (ws_size < 4*BUFB) return;
    // R2: O f16 (proj GEMM + fixup operand; exact)
    ushort* of16 = (ushort*)(ws + 2*BUFB);
    // R3: xh f16 | w3h | wph | bits | flag bitmaps
    char* r3 = ws + 3*BUFB;
    ushort* xh   = (ushort*)r3;                            // 12.9 MB
    ushort* w3h  = (ushort*)(r3 + (13u<<20));              // 1.5 MB
    ushort* wph  = (ushort*)(r3 + (15u<<20));              // 0.5 MB
    u64*    bits3 = (u64*)(r3 + (16u<<20));                // 2.42 MB
    u64*    qbits = bits3;
    u64*    kbits = bits3 + MH;
    u64*    vbits = bits3 + 2*(size_t)MH;
    u64*    fmap3 = (u64*)(r3 + (19u<<20));                // 605 KB
    u64*    fmapp = (u64*)(r3 + (20u<<20));                // 202 KB

    // f32 -> f16 conversions
    cvt16<<<TENSOR_ELEMS/1024, 256, 0, stream>>>(x, xh, TENSOR_ELEMS);
    cvt16<<<WELEMS/1024, 256, 0, stream>>>(Wq, w3h,            WELEMS);
    cvt16<<<WELEMS/1024, 256, 0, stream>>>(Wk, w3h +   WELEMS, WELEMS);
    cvt16<<<WELEMS/1024, 256, 0, stream>>>(Wv, w3h + 2*WELEMS, WELEMS);
    cvt16<<<WELEMS/1024, 256, 0, stream>>>(Wp, wph,            WELEMS);

    // QKV projections fused with LIF + bit-pack: grid 99 x (4 col x 3 w)
    gemm_qkv_lif<<<99*12, 256, 0, stream>>>(xh, w3h, bits3, fmap3);
    // exact f64 fixup of flagged chains (corrects single spike bits)
    fixup_qkv<<<2048, 256, 0, stream>>>(x, Wq, Wk, Wv, bits3, fmap3);

    // attention (exact integer math via bf16 MFMA on 0/1 spikes)
    attn_qk<<<dim3(T_*B_, H_), 256, 0, stream>>>(qbits, kbits, attn_out);
    attn_pv<<<dim3(T_*B_, H_, 2), 256, 0, stream>>>(attn_out, vbits, of16);

    // output projection fused with bias + LIF -> out_spk + flag bitmap
    gemm_proj_lif<<<99*4, 256, 0, stream>>>(of16, wph, bp, out_spk, fmapp);
    fixup_proj<<<1024, 256, 0, stream>>>(of16, Wp, bp, out_spk, fmapp);
}

// Round 10
// 168.896 us; speedup vs baseline: 3.4839x; 1.0746x over previous
//
#include <hip/hip_runtime.h>
#include <stdint.h>

// Problem constants
#define T_ 4
#define B_ 16
#define N_ 197
#define D_ 512
#define H_ 8
#define DH 64
#define BN_ (B_*N_)              // 3152 rows per timestep
#define PLANE (BN_*D_)           // 1,613,824 elems per t-plane
#define M_ (T_*BN_)              // 12608 GEMM rows
#define TENSOR_ELEMS (T_*PLANE)  // 6,455,296 elems per (T,B,N,D) tensor
#define WELEMS (D_*D_)           // 262,144
#define MH (M_*H_)               // 100,864 bitmask words per tensor
#define FLAG_TOL 6e-3f           // ~13 sigma of single-pass f16 dot error
#define NFW3 (3*PLANE/64)        // 75,648 flag words (qkv)
#define NFWP (PLANE/64)          // 25,216 flag words (proj / per tensor)

typedef __attribute__((ext_vector_type(8))) short short8v;
typedef __attribute__((ext_vector_type(8))) _Float16 f16x8;
typedef __attribute__((ext_vector_type(4))) float f32x4;
typedef __attribute__((ext_vector_type(16))) float f32x16;
typedef __attribute__((ext_vector_type(4))) unsigned short ushort4v;
typedef unsigned long long u64;
typedef unsigned int u32;

__device__ __forceinline__ ushort f16_bits(float f) {
    _Float16 h = (_Float16)f;                      // v_cvt_f16_f32, RNE
    return __builtin_bit_cast(unsigned short, h);
}
__device__ __forceinline__ float f16_val(ushort u) {
    return (float)__builtin_bit_cast(_Float16, u);
}

// async global->LDS 16B copy (one per lane; dest = wave base + lane*16)
__device__ __forceinline__ void gload16(const void* g, void* l) {
    __builtin_amdgcn_global_load_lds(
        (const __attribute__((address_space(1))) unsigned int*)g,
        (__attribute__((address_space(3))) unsigned int*)l, 16, 0, 0);
}

// 8 spike bits -> bf16 0/1 fragment
__device__ __forceinline__ short8v unpack8(u32 bits) {
    short8v r;
    #pragma unroll
    for (int j = 0; j < 8; ++j)
        r[j] = (short)(((bits >> j) & 1u) ? 0x3F80 : 0);
    return r;
}

// ---------------------------------------------------------------------------
// f32 -> f16 convert (RNE)
// ---------------------------------------------------------------------------
__global__ void cvt16(const float* __restrict__ src, ushort* __restrict__ dst, int n)
{
    int i = (blockIdx.x*256 + threadIdx.x)*4;
    if (i >= n) return;
    float4 v = *(const float4*)(src + i);
    ushort4v o;
    o[0] = f16_bits(v.x); o[1] = f16_bits(v.y);
    o[2] = f16_bits(v.z); o[3] = f16_bits(v.w);
    *(ushort4v*)(dst + i) = o;
}

// ---------------------------------------------------------------------------
// Fused f16 GEMM + LIF + spike-bit pack (QKV), 2-phase double-buffered.
// Tile: 32 BN-rows x 128 cols x all 4 timesteps. Per wave: 32 cols, acc[4 t].
// ---------------------------------------------------------------------------
__global__ __launch_bounds__(256)
void gemm_qkv_lif(const ushort* __restrict__ xh, const ushort* __restrict__ w3h,
                  u64* __restrict__ bits3, u64* __restrict__ fmap3)
{
    __shared__ __align__(16) ushort smem[32768];   // dbuf x (A 16KB | B 16KB)
    const int tid = threadIdx.x;
    const int lane = tid & 63, wn = tid >> 6;      // wave owns 32 cols
    const int l31 = lane & 31, lg = lane >> 5;
    const int nyz = 12, nz = 3;

    // bijective XCD swizzle + yz-fastest decode
    int nwg = gridDim.x, orig = blockIdx.x;
    int q8 = nwg >> 3, r8 = nwg & 7, xcd = orig & 7, loc = orig >> 3;
    int wg = (xcd < r8 ? xcd*(q8+1) : r8*(q8+1) + (xcd-r8)*q8) + loc;
    int bx = wg / nyz, yz = wg - bx*nyz;
    int by = yz / nz,  z  = yz - by*nz;

    const int bm0 = bx * 32;                       // row offset within BN_
    const int bn0 = by * 128;
    const ushort* Wz = w3h + (size_t)z * WELEMS;

    f32x16 acc[4];
    #pragma unroll
    for (int t = 0; t < 4; ++t)
        #pragma unroll
        for (int r = 0; r < 16; ++r) acc[t][r] = 0.f;

    auto STAGE = [&](int buf, int kt) {
        #pragma unroll
        for (int i = 0; i < 8; ++i) {
            const int q = ((i & 3) << 8) | tid;    // chunk id [0,1024)
            const int row = q & 127, c = q >> 7;   // LDS [c][row128][8]
            ushort* dst = smem + buf*16384 + ((i >> 2) << 13) + q*8;
            if (i < 4) {
                int t = row >> 5, r32 = row & 31;
                if (bm0 + r32 < BN_)
                    gload16(xh + ((size_t)(t*BN_ + bm0 + r32)*D_ + kt + c*8), dst);
            } else {
                gload16(Wz + ((size_t)(bn0 + row)*D_ + kt + c*8), dst);
            }
        }
    };
    auto COMPUTE = [&](int buf) {
        const ushort* base = smem + buf*16384;
        #pragma unroll
        for (int s = 0; s < 4; ++s) {
            const int cA = (s << 1) | lg;
            f16x8 bv = *(const f16x8*)&base[8192 + (cA*128 + wn*32 + l31)*8];
            #pragma unroll
            for (int t = 0; t < 4; ++t) {
                f16x8 av = *(const f16x8*)&base[(cA*128 + t*32 + l31)*8];
                acc[t] = __builtin_amdgcn_mfma_f32_32x32x16_f16(av, bv, acc[t], 0, 0, 0);
            }
        }
    };

    STAGE(0, 0);
    __syncthreads();
    int cur = 0;
    #pragma unroll
    for (int k64 = 0; k64 < 8; ++k64) {
        if (k64 < 7) STAGE(cur ^ 1, (k64 + 1)*64);
        COMPUTE(cur);
        __syncthreads();
        cur ^= 1;
    }

    // ---- fused LIF epilogue ----
    // acc[t][r]: row32 = (r&3)+8*(r>>2)+4*lg, col = bn0 + wn*32 + l31
    u32* sp = (u32*)smem;          // [wn][t][r][lg] spike halves (512 u32)
    u32* fl = (u32*)smem + 512;    // [wn][r][lg] flag halves (128 u32)
    #pragma unroll
    for (int r = 0; r < 16; ++r) {
        bool s[4]; bool fg = false; float v = 0.f;
        #pragma unroll
        for (int t = 0; t < 4; ++t) {
            float h = v + (acc[t][r] - v)*0.5f;
            s[t] = h >= 1.0f;
            fg |= fabsf(h - 1.0f) < FLAG_TOL;
            v = s[t] ? 0.f : h;
        }
        #pragma unroll
        for (int t = 0; t < 4; ++t) {
            u64 m = __ballot(s[t]);
            if (lane == 0) {
                sp[((wn*4 + t)*16 + r)*2 + 0] = (u32)m;
                sp[((wn*4 + t)*16 + r)*2 + 1] = (u32)(m >> 32);
            }
        }
        u64 fm = __ballot(fg);
        if (lane == 0) {
            fl[(wn*16 + r)*2 + 0] = (u32)fm;
            fl[(wn*16 + r)*2 + 1] = (u32)(fm >> 32);
        }
    }
    __syncthreads();
    // assemble + store: word(h_local) = low32 from wn=2h, high32 from wn=2h+1
    {
        int t = tid >> 6, row32 = (tid >> 1) & 31, hl = tid & 1;
        int rr = (row32 & 3) | ((row32 >> 3) << 2);
        int lgg = (row32 >> 2) & 1;
        u64 word = (u64)sp[(((2*hl)*4 + t)*16 + rr)*2 + lgg]
                 | ((u64)sp[(((2*hl+1)*4 + t)*16 + rr)*2 + lgg] << 32);
        if (bm0 + row32 < BN_)
            bits3[(size_t)z*MH + (size_t)(t*BN_ + bm0 + row32)*H_ + (bn0 >> 6) + hl] = word;
        if (tid < 64) {
            int rowf = tid >> 1, hlf = tid & 1;
            int rf = (rowf & 3) | ((rowf >> 3) << 2);
            int lgf = (rowf >> 2) & 1;
            u64 fw = (u64)fl[((2*hlf)*16 + rf)*2 + lgf]
                   | ((u64)fl[((2*hlf+1)*16 + rf)*2 + lgf] << 32);
            if (bm0 + rowf < BN_)
                fmap3[(size_t)z*NFWP + (size_t)(bm0 + rowf)*8 + (bn0 >> 6) + hlf] = fw;
        }
    }
}

// ---------------------------------------------------------------------------
// Fused f16 GEMM + bias + LIF (proj), 2-phase double-buffered.
// ---------------------------------------------------------------------------
__global__ __launch_bounds__(256)
void gemm_proj_lif(const ushort* __restrict__ oh, const ushort* __restrict__ wph,
                   const float* __restrict__ bias, float* __restrict__ outp,
                   u64* __restrict__ fmapp)
{
    __shared__ __align__(16) ushort smem[32768];
    const int tid = threadIdx.x;
    const int lane = tid & 63, wn = tid >> 6;
    const int l31 = lane & 31, lg = lane >> 5;
    const int nyz = 4;

    int nwg = gridDim.x, orig = blockIdx.x;
    int q8 = nwg >> 3, r8 = nwg & 7, xcd = orig & 7, loc = orig >> 3;
    int wg = (xcd < r8 ? xcd*(q8+1) : r8*(q8+1) + (xcd-r8)*q8) + loc;
    int bx = wg / nyz, by = wg - bx*nyz;

    const int bm0 = bx * 32, bn0 = by * 128;

    f32x16 acc[4];
    #pragma unroll
    for (int t = 0; t < 4; ++t)
        #pragma unroll
        for (int r = 0; r < 16; ++r) acc[t][r] = 0.f;

    auto STAGE = [&](int buf, int kt) {
        #pragma unroll
        for (int i = 0; i < 8; ++i) {
            const int q = ((i & 3) << 8) | tid;
            const int row = q & 127, c = q >> 7;
            ushort* dst = smem + buf*16384 + ((i >> 2) << 13) + q*8;
            if (i < 4) {
                int t = row >> 5, r32 = row & 31;
                if (bm0 + r32 < BN_)
                    gload16(oh + ((size_t)(t*BN_ + bm0 + r32)*D_ + kt + c*8), dst);
            } else {
                gload16(wph + ((size_t)(bn0 + row)*D_ + kt + c*8), dst);
            }
        }
    };
    auto COMPUTE = [&](int buf) {
        const ushort* base = smem + buf*16384;
        #pragma unroll
        for (int s = 0; s < 4; ++s) {
            const int cA = (s << 1) | lg;
            f16x8 bv = *(const f16x8*)&base[8192 + (cA*128 + wn*32 + l31)*8];
            #pragma unroll
            for (int t = 0; t < 4; ++t) {
                f16x8 av = *(const f16x8*)&base[(cA*128 + t*32 + l31)*8];
                acc[t] = __builtin_amdgcn_mfma_f32_32x32x16_f16(av, bv, acc[t], 0, 0, 0);
            }
        }
    };

    STAGE(0, 0);
    __syncthreads();
    int cur = 0;
    #pragma unroll
    for (int k64 = 0; k64 < 8; ++k64) {
        if (k64 < 7) STAGE(cur ^ 1, (k64 + 1)*64);
        COMPUTE(cur);
        __syncthreads();
        cur ^= 1;
    }

    const int gcol = bn0 + wn*32 + l31;
    const float bb = bias[gcol];
    u32* fl = (u32*)smem;          // [wn][r][lg] flag halves
    #pragma unroll
    for (int r = 0; r < 16; ++r) {
        const int row32 = (r & 3) + 8*(r >> 2) + 4*lg;
        const bool live = bm0 + row32 < BN_;
        bool fg = false; float v = 0.f;
        #pragma unroll
        for (int t = 0; t < 4; ++t) {
            float h = v + ((acc[t][r] + bb) - v)*0.5f;
            bool st = h >= 1.0f;
            fg |= fabsf(h - 1.0f) < FLAG_TOL;
            if (live)
                outp[(size_t)t*PLANE + (size_t)(bm0 + row32)*D_ + gcol] = st ? 1.0f : 0.0f;
            v = st ? 0.f : h;
        }
        u64 fm = __ballot(fg);
        if (lane == 0) {
            fl[(wn*16 + r)*2 + 0] = (u32)fm;
            fl[(wn*16 + r)*2 + 1] = (u32)(fm >> 32);
        }
    }
    __syncthreads();
    if (tid < 64) {
        int rowf = tid >> 1, hlf = tid & 1;
        int rf = (rowf & 3) | ((rowf >> 3) << 2);
        int lgf = (rowf >> 2) & 1;
        u64 fw = (u64)fl[((2*hlf)*16 + rf)*2 + lgf]
               | ((u64)fl[((2*hlf+1)*16 + rf)*2 + lgf] << 32);
        if (bm0 + rowf < BN_)
            fmapp[(size_t)(bm0 + rowf)*8 + (bn0 >> 6) + hlf] = fw;
    }
}

// ---------------------------------------------------------------------------
// f64 exact recompute of flagged chains (bitmap scan, 4 waves/block, ILP).
// ---------------------------------------------------------------------------
__global__ __launch_bounds__(256)
void fixup_qkv(const float* __restrict__ x,
               const float* __restrict__ Wq, const float* __restrict__ Wk,
               const float* __restrict__ Wv,
               u64* __restrict__ bits3, const u64* __restrict__ flagmap)
{
    const int lane = threadIdx.x & 63;
    const int wv = blockIdx.x*4 + (threadIdx.x >> 6);
    const int nw = gridDim.x*4;
    for (int w = wv; w < NFW3; w += nw) {
        u64 fm = flagmap[w];
        while (fm) {
            int bit = __ffsll((long long)fm) - 1;
            fm &= fm - 1;
            int id = (w << 6) + bit;
            int tsr = id / PLANE;
            int rem = id - tsr*PLANE;
            int r = rem >> 9, e = rem & (D_-1);
            const float* W = (tsr==0) ? Wq : (tsr==1 ? Wk : Wv);
            const float* wr = W + (size_t)e*D_;
            u64* bits = bits3 + (size_t)tsr*MH;
            float wv8[8];
            #pragma unroll
            for (int i = 0; i < 8; ++i) wv8[i] = wr[lane + 64*i];
            double dots[T_];
            #pragma unroll
            for (int t = 0; t < T_; ++t) {
                const float* xr = x + (size_t)(t*BN_ + r)*D_;
                float xv8[8];
                #pragma unroll
                for (int i = 0; i < 8; ++i) xv8[i] = xr[lane + 64*i];
                double p = 0.0;
                #pragma unroll
                for (int i = 0; i < 8; ++i) p += (double)xv8[i]*(double)wv8[i];
                dots[t] = p;
            }
            #pragma unroll
            for (int off = 32; off > 0; off >>= 1)
                #pragma unroll
                for (int t = 0; t < T_; ++t)
                    dots[t] += __shfl_down(dots[t], off);
            if (lane == 0) {
                double v = 0.0;
                u64 b = 1ull << (e & 63);
                #pragma unroll
                for (int t = 0; t < T_; ++t) {
                    double hh = v + (dots[t] - v)/2.0;
                    bool s = hh >= 1.0;
                    size_t wd = (size_t)(t*BN_ + r)*H_ + (e >> 6);
                    if (s) atomicOr(&bits[wd], b);
                    else   atomicAnd(&bits[wd], ~b);
                    v = s ? 0.0 : hh;
                }
            }
        }
    }
}

// ---------------------------------------------------------------------------
// Fused MFMA attention: per (tb,h) block. Q/K fragments unpacked DIRECTLY
// from spike bit-words (no Q/K staging); per strip: QK^T -> attn_map write +
// bf16 S strip in per-wave LDS (exact) -> PV against Vt -> of16.
// ---------------------------------------------------------------------------
#define JP 224   // 7 * 32 (padded j for PV K-dim)
#define VSTR 232 // LDS row stride for Vt / Ss

__global__ __launch_bounds__(256)
void attn_fused(const u64* __restrict__ qbits, const u64* __restrict__ kbits,
                const u64* __restrict__ vbits,
                float* __restrict__ attn_out, ushort* __restrict__ of16)
{
    __shared__ ushort Vt[DH][VSTR];
    __shared__ ushort Ss[4][16][VSTR];
    int tb = blockIdx.x, h = blockIdx.y;
    int tid = threadIdx.x, wave = tid >> 6, lane = tid & 63;

    // stage V transposed from vbits: Vt[d][j], j >= N_ zeroed
    for (int idx = tid; idx < JP*16; idx += 256) {
        int j = idx >> 4, d4 = (idx & 15) << 2;
        ushort vv[4] = {0,0,0,0};
        if (j < N_) {
            u64 vw = vbits[((size_t)tb*N_ + j)*H_ + h];
            #pragma unroll
            for (int r = 0; r < 4; ++r)
                vv[r] = ((vw >> (d4+r)) & 1ull) ? 0x3F80 : 0;
        }
        Vt[d4+0][j]=vv[0]; Vt[d4+1][j]=vv[1]; Vt[d4+2][j]=vv[2]; Vt[d4+3][j]=vv[3];
    }
    // zero Ss pad cols [208, 224)
    for (int idx = lane; idx < 16*16; idx += 64)
        Ss[wave][idx >> 4][208 + (idx & 15)] = 0;
    __syncthreads();

    const int il = lane & 15, kk = (lane >> 4) << 3, ig = (lane >> 4) << 2;
    const size_t amap = ((size_t)tb*H_ + h)*(size_t)(N_*N_);

    for (int it = wave; it < 13; it += 4) {
        int i0 = it << 4;
        // A-fragments straight from qbits (row i0+il, d-bits kk..kk+7 / +32)
        int qrow = i0 + il;
        u64 qw = (qrow < N_) ? qbits[((size_t)tb*N_ + qrow)*H_ + h] : 0ull;
        short8v a0 = unpack8((u32)(qw >> kk));
        short8v a1 = unpack8((u32)((qw >> 32) >> kk));
        // QK^T over 13 col-tiles; write attn_map + stash bf16 S strip
        for (int jt = 0; jt < 13; ++jt) {
            int j0 = jt << 4, jrow = j0 + il;
            u64 kw = (jrow < N_) ? kbits[((size_t)tb*N_ + jrow)*H_ + h] : 0ull;
            short8v b0 = unpack8((u32)(kw >> kk));
            short8v b1 = unpack8((u32)((kw >> 32) >> kk));
            f32x4 c = {0.f, 0.f, 0.f, 0.f};
            c = __builtin_amdgcn_mfma_f32_16x16x32_bf16(a0, b0, c, 0, 0, 0);
            c = __builtin_amdgcn_mfma_f32_16x16x32_bf16(a1, b1, c, 0, 0, 0);
            int j = j0 + il;               // C col = lane&15
            #pragma unroll
            for (int r = 0; r < 4; ++r) {
                float sv = c[r]*0.125f;    // exact: k/8, k <= 64
                int i = i0 + ig + r;       // C row = (lane>>4)*4 + r
                if (i < N_ && j < N_)
                    attn_out[amap + (size_t)i*N_ + j] = sv;
                Ss[wave][ig + r][j] = (ushort)(__float_as_uint(sv) >> 16);
            }
        }
        // PV for this strip (per-wave Ss; same-wave LDS ordering suffices)
        f32x4 o[4];
        #pragma unroll
        for (int dt = 0; dt < 4; ++dt) o[dt] = (f32x4){0.f,0.f,0.f,0.f};
        #pragma unroll
        for (int kt = 0; kt < 7; ++kt) {
            short8v a = *(const short8v*)&Ss[wave][il][kt*32 + kk];
            #pragma unroll
            for (int dt = 0; dt < 4; ++dt) {
                short8v b = *(const short8v*)&Vt[dt*16 + il][kt*32 + kk];
                o[dt] = __builtin_amdgcn_mfma_f32_16x16x32_bf16(a, b, o[dt], 0, 0, 0);
            }
        }
        #pragma unroll
        for (int dt = 0; dt < 4; ++dt)
            #pragma unroll
            for (int r = 0; r < 4; ++r) {
                int i = i0 + ig + r;
                if (i < N_)
                    of16[((size_t)tb*N_ + i)*D_ + (size_t)h*DH + dt*16 + il] =
                        f16_bits(o[dt][r]);
            }
    }
}

// ---------------------------------------------------------------------------
// fixup_proj: exact f64 recompute of flagged proj chains (reads of16, exact).
// ---------------------------------------------------------------------------
__global__ __launch_bounds__(256)
void fixup_proj(const ushort* __restrict__ of16, const float* __restrict__ Wp,
                const float* __restrict__ bp, float* __restrict__ outp,
                const u64* __restrict__ flagmap)
{
    const int lane = threadIdx.x & 63;
    const int wv = blockIdx.x*4 + (threadIdx.x >> 6);
    const int nw = gridDim.x*4;
    for (int w = wv; w < NFWP; w += nw) {
        u64 fm = flagmap[w];
        while (fm) {
            int bit = __ffsll((long long)fm) - 1;
            fm &= fm - 1;
            int rem = (w << 6) + bit;
            int r = rem >> 9, e = rem & (D_-1);
            const float* wr = Wp + (size_t)e*D_;
            float wv8[8];
            #pragma unroll
            for (int i = 0; i < 8; ++i) wv8[i] = wr[lane + 64*i];
            double dots[T_];
            #pragma unroll
            for (int t = 0; t < T_; ++t) {
                const ushort* ar = of16 + (size_t)(t*BN_ + r)*D_;
                float av8[8];
                #pragma unroll
                for (int i = 0; i < 8; ++i) av8[i] = f16_val(ar[lane + 64*i]);
                double p = 0.0;
                #pragma unroll
                for (int i = 0; i < 8; ++i) p += (double)av8[i]*(double)wv8[i];
                dots[t] = p;
            }
            #pragma unroll
            for (int off = 32; off > 0; off >>= 1)
                #pragma unroll
                for (int t = 0; t < T_; ++t)
                    dots[t] += __shfl_down(dots[t], off);
            if (lane == 0) {
                double v = 0.0;
                #pragma unroll
                for (int t = 0; t < T_; ++t) {
                    double xt = dots[t] + (double)bp[e];
                    double h = v + (xt - v)/2.0;
                    bool s = h >= 1.0;
                    outp[(size_t)t*PLANE + rem] = s ? 1.0f : 0.0f;
                    v = s ? 0.0 : h;
                }
            }
        }
    }
}

// ---------------------------------------------------------------------------
extern "C" void kernel_launch(void* const* d_in, const int* in_sizes, int n_in,
                              void* d_out, int out_size, void* d_ws, size_t ws_size,
                              hipStream_t stream)
{
    const float* x  = (const float*)d_in[0];
    const float* Wq = (const float*)d_in[1];
    const float* Wk = (const float*)d_in[2];
    const float* Wv = (const float*)d_in[3];
    const float* Wp = (const float*)d_in[4];
    const float* bp = (const float*)d_in[5];
    float* out_spk  = (float*)d_out;                       // (T,B,N,D) spikes
    float* attn_out = (float*)d_out + TENSOR_ELEMS;        // (T,B,H,N,N)

    char* ws = (char*)d_ws;
    const size_t BUFB = (size_t)TENSOR_ELEMS * sizeof(float);   // 25.8 MB
    if (ws_size < 4*BUFB) return;
    // R2: O f16 (proj GEMM + fixup operand; exact)
    ushort* of16 = (ushort*)(ws + 2*BUFB);
    // R3: xh f16 | w3h | wph | bits | flag bitmaps
    char* r3 = ws + 3*BUFB;
    ushort* xh   = (ushort*)r3;                            // 12.9 MB
    ushort* w3h  = (ushort*)(r3 + (13u<<20));              // 1.5 MB
    ushort* wph  = (ushort*)(r3 + (15u<<20));              // 0.5 MB
    u64*    bits3 = (u64*)(r3 + (16u<<20));                // 2.42 MB
    u64*    qbits = bits3;
    u64*    kbits = bits3 + MH;
    u64*    vbits = bits3 + 2*(size_t)MH;
    u64*    fmap3 = (u64*)(r3 + (19u<<20));                // 605 KB
    u64*    fmapp = (u64*)(r3 + (20u<<20));                // 202 KB

    // f32 -> f16 conversions
    cvt16<<<TENSOR_ELEMS/1024, 256, 0, stream>>>(x, xh, TENSOR_ELEMS);
    cvt16<<<WELEMS/1024, 256, 0, stream>>>(Wq, w3h,            WELEMS);
    cvt16<<<WELEMS/1024, 256, 0, stream>>>(Wk, w3h +   WELEMS, WELEMS);
    cvt16<<<WELEMS/1024, 256, 0, stream>>>(Wv, w3h + 2*WELEMS, WELEMS);
    cvt16<<<WELEMS/1024, 256, 0, stream>>>(Wp, wph,            WELEMS);

    // QKV projections fused with LIF + bit-pack: grid 99 x (4 col x 3 w)
    gemm_qkv_lif<<<99*12, 256, 0, stream>>>(xh, w3h, bits3, fmap3);
    // exact f64 fixup of flagged chains (corrects single spike bits)
    fixup_qkv<<<2048, 256, 0, stream>>>(x, Wq, Wk, Wv, bits3, fmap3);

    // fused attention: QK^T -> attn_map + PV -> of16 (exact integer math)
    attn_fused<<<dim3(T_*B_, H_), 256, 0, stream>>>(
        qbits, kbits, vbits, attn_out, of16);

    // output projection fused with bias + LIF -> out_spk + flag bitmap
    gemm_proj_lif<<<99*4, 256, 0, stream>>>(of16, wph, bp, out_spk, fmapp);
    fixup_proj<<<1024, 256, 0, stream>>>(of16, Wp, bp, out_spk, fmapp);
}

// Round 12
// 159.695 us; speedup vs baseline: 3.6847x; 1.0576x over previous
//
#include <hip/hip_runtime.h>
#include <stdint.h>

// Problem constants
#define T_ 4
#define B_ 16
#define N_ 197
#define D_ 512
#define H_ 8
#define DH 64
#define BN_ (B_*N_)              // 3152 rows per timestep
#define PLANE (BN_*D_)           // 1,613,824 elems per t-plane
#define M_ (T_*BN_)              // 12608 GEMM rows
#define TENSOR_ELEMS (T_*PLANE)  // 6,455,296 elems per (T,B,N,D) tensor
#define WELEMS (D_*D_)           // 262,144
#define MH (M_*H_)               // 100,864 bitmask words per tensor
#define FLAG_TOL 6e-3f           // ~13 sigma of single-pass f16 dot error
#define NFW3 (3*PLANE/64)        // 75,648 flag words (qkv)
#define NFWP (PLANE/64)          // 25,216 flag words (proj)

typedef __attribute__((ext_vector_type(8))) short short8v;
typedef __attribute__((ext_vector_type(8))) _Float16 f16x8;
typedef __attribute__((ext_vector_type(4))) float f32x4;
typedef __attribute__((ext_vector_type(16))) float f32x16;
typedef __attribute__((ext_vector_type(4))) unsigned short ushort4v;
typedef unsigned long long u64;
typedef unsigned int u32;

__device__ __forceinline__ ushort f16_bits(float f) {
    _Float16 h = (_Float16)f;                      // v_cvt_f16_f32, RNE
    return __builtin_bit_cast(unsigned short, h);
}
__device__ __forceinline__ float f16_val(ushort u) {
    return (float)__builtin_bit_cast(_Float16, u);
}

// async global->LDS 16B copy (one per lane; dest = wave base + lane*16)
__device__ __forceinline__ void gload16(const void* g, void* l) {
    __builtin_amdgcn_global_load_lds(
        (const __attribute__((address_space(1))) unsigned int*)g,
        (__attribute__((address_space(3))) unsigned int*)l, 16, 0, 0);
}

// 8 spike bits -> bf16 0/1 fragment
__device__ __forceinline__ short8v unpack8(u32 bits) {
    short8v r;
    #pragma unroll
    for (int j = 0; j < 8; ++j)
        r[j] = (short)(((bits >> j) & 1u) ? 0x3F80 : 0);
    return r;
}

// ---------------------------------------------------------------------------
// Batched f32 -> f16 convert (x + Wq + Wk + Wv + Wp in one launch)
// ---------------------------------------------------------------------------
#define NBX (TENSOR_ELEMS/1024)  // 6304
#define NBW (WELEMS/1024)        // 256

__global__ void cvt_all(const float* __restrict__ x,  const float* __restrict__ Wq,
                        const float* __restrict__ Wk, const float* __restrict__ Wv,
                        const float* __restrict__ Wp,
                        ushort* __restrict__ xh, ushort* __restrict__ w3h,
                        ushort* __restrict__ wph)
{
    int b = blockIdx.x;
    const float* src; ushort* dst; int base;
    if      (b < NBX)         { src = x;  dst = xh;             base = b; }
    else if (b < NBX + NBW)   { src = Wq; dst = w3h;            base = b - NBX; }
    else if (b < NBX + 2*NBW) { src = Wk; dst = w3h + WELEMS;   base = b - NBX - NBW; }
    else if (b < NBX + 3*NBW) { src = Wv; dst = w3h + 2*WELEMS; base = b - NBX - 2*NBW; }
    else                      { src = Wp; dst = wph;            base = b - NBX - 3*NBW; }
    int i = (base*256 + threadIdx.x)*4;
    float4 v = *(const float4*)(src + i);
    ushort4v o;
    o[0] = f16_bits(v.x); o[1] = f16_bits(v.y);
    o[2] = f16_bits(v.z); o[3] = f16_bits(v.w);
    *(ushort4v*)(dst + i) = o;
}

// ---------------------------------------------------------------------------
// Fused f16 GEMM + LIF + spike-bit pack (QKV). BK=32 double-buffer (32 KB LDS
// -> 4 blocks/CU). Tile: 32 BN-rows x 128 cols x all 4 timesteps.
// ---------------------------------------------------------------------------
__global__ __launch_bounds__(256, 4)
void gemm_qkv_lif(const ushort* __restrict__ xh, const ushort* __restrict__ w3h,
                  u64* __restrict__ bits3, u64* __restrict__ fmap3)
{
    __shared__ __align__(16) ushort smem[16384];   // dbuf x (A 8KB | B 8KB)
    const int tid = threadIdx.x;
    const int lane = tid & 63, wn = tid >> 6;      // wave owns 32 cols
    const int l31 = lane & 31, lg = lane >> 5;
    const int nyz = 12, nz = 3;

    // bijective XCD swizzle + yz-fastest decode
    int nwg = gridDim.x, orig = blockIdx.x;
    int q8 = nwg >> 3, r8 = nwg & 7, xcd = orig & 7, loc = orig >> 3;
    int wg = (xcd < r8 ? xcd*(q8+1) : r8*(q8+1) + (xcd-r8)*q8) + loc;
    int bx = wg / nyz, yz = wg - bx*nyz;
    int by = yz / nz,  z  = yz - by*nz;

    const int bm0 = bx * 32;                       // row offset within BN_
    const int bn0 = by * 128;
    const ushort* Wz = w3h + (size_t)z * WELEMS;

    f32x16 acc[4];
    #pragma unroll
    for (int t = 0; t < 4; ++t)
        #pragma unroll
        for (int r = 0; r < 16; ++r) acc[t][r] = 0.f;

    auto STAGE = [&](int buf, int kt) {
        #pragma unroll
        for (int i = 0; i < 4; ++i) {
            const int q = ((i & 1) << 8) | tid;    // chunk id [0,512)
            const int row = q & 127, c = q >> 7;   // LDS [c][row128][8]
            ushort* dst = smem + buf*8192 + ((i >> 1) << 12) + q*8;
            if (i < 2) {
                int t = row >> 5, r32 = row & 31;
                if (bm0 + r32 < BN_)
                    gload16(xh + ((size_t)(t*BN_ + bm0 + r32)*D_ + kt + c*8), dst);
            } else {
                gload16(Wz + ((size_t)(bn0 + row)*D_ + kt + c*8), dst);
            }
        }
    };
    auto COMPUTE = [&](int buf) {
        const ushort* base = smem + buf*8192;
        #pragma unroll
        for (int s = 0; s < 2; ++s) {
            const int cA = (s << 1) | lg;
            f16x8 bv = *(const f16x8*)&base[4096 + (cA*128 + wn*32 + l31)*8];
            #pragma unroll
            for (int t = 0; t < 4; ++t) {
                f16x8 av = *(const f16x8*)&base[(cA*128 + t*32 + l31)*8];
                acc[t] = __builtin_amdgcn_mfma_f32_32x32x16_f16(av, bv, acc[t], 0, 0, 0);
            }
        }
    };

    STAGE(0, 0);
    __syncthreads();
    int cur = 0;
    #pragma unroll
    for (int k32 = 0; k32 < 16; ++k32) {
        if (k32 < 15) STAGE(cur ^ 1, (k32 + 1)*32);
        COMPUTE(cur);
        __syncthreads();
        cur ^= 1;
    }

    // ---- fused LIF epilogue ----
    // acc[t][r]: row32 = (r&3)+8*(r>>2)+4*lg, col = bn0 + wn*32 + l31
    u32* sp = (u32*)smem;          // [wn][t][r][lg] spike halves (512 u32)
    u32* fl = (u32*)smem + 512;    // [wn][r][lg] flag halves (128 u32)
    #pragma unroll
    for (int r = 0; r < 16; ++r) {
        bool s[4]; bool fg = false; float v = 0.f;
        #pragma unroll
        for (int t = 0; t < 4; ++t) {
            float h = v + (acc[t][r] - v)*0.5f;
            s[t] = h >= 1.0f;
            fg |= fabsf(h - 1.0f) < FLAG_TOL;
            v = s[t] ? 0.f : h;
        }
        #pragma unroll
        for (int t = 0; t < 4; ++t) {
            u64 m = __ballot(s[t]);
            if (lane == 0) {
                sp[((wn*4 + t)*16 + r)*2 + 0] = (u32)m;
                sp[((wn*4 + t)*16 + r)*2 + 1] = (u32)(m >> 32);
            }
        }
        u64 fm = __ballot(fg);
        if (lane == 0) {
            fl[(wn*16 + r)*2 + 0] = (u32)fm;
            fl[(wn*16 + r)*2 + 1] = (u32)(fm >> 32);
        }
    }
    __syncthreads();
    // assemble + store: word(h_local) = low32 from wn=2h, high32 from wn=2h+1
    {
        int t = tid >> 6, row32 = (tid >> 1) & 31, hl = tid & 1;
        int rr = (row32 & 3) | ((row32 >> 3) << 2);
        int lgg = (row32 >> 2) & 1;
        u64 word = (u64)sp[(((2*hl)*4 + t)*16 + rr)*2 + lgg]
                 | ((u64)sp[(((2*hl+1)*4 + t)*16 + rr)*2 + lgg] << 32);
        if (bm0 + row32 < BN_)
            bits3[(size_t)z*MH + (size_t)(t*BN_ + bm0 + row32)*H_ + (bn0 >> 6) + hl] = word;
        if (tid < 64) {
            int rowf = tid >> 1, hlf = tid & 1;
            int rf = (rowf & 3) | ((rowf >> 3) << 2);
            int lgf = (rowf >> 2) & 1;
            u64 fw = (u64)fl[((2*hlf)*16 + rf)*2 + lgf]
                   | ((u64)fl[((2*hlf+1)*16 + rf)*2 + lgf] << 32);
            if (bm0 + rowf < BN_)
                fmap3[(size_t)z*NFWP + (size_t)(bm0 + rowf)*8 + (bn0 >> 6) + hlf] = fw;
        }
    }
}

// ---------------------------------------------------------------------------
// Fused f16 GEMM + bias + LIF (proj). BK=32 double-buffer.
// ---------------------------------------------------------------------------
__global__ __launch_bounds__(256, 4)
void gemm_proj_lif(const ushort* __restrict__ oh, const ushort* __restrict__ wph,
                   const float* __restrict__ bias, float* __restrict__ outp,
                   u64* __restrict__ fmapp)
{
    __shared__ __align__(16) ushort smem[16384];
    const int tid = threadIdx.x;
    const int lane = tid & 63, wn = tid >> 6;
    const int l31 = lane & 31, lg = lane >> 5;
    const int nyz = 4;

    int nwg = gridDim.x, orig = blockIdx.x;
    int q8 = nwg >> 3, r8 = nwg & 7, xcd = orig & 7, loc = orig >> 3;
    int wg = (xcd < r8 ? xcd*(q8+1) : r8*(q8+1) + (xcd-r8)*q8) + loc;
    int bx = wg / nyz, by = wg - bx*nyz;

    const int bm0 = bx * 32, bn0 = by * 128;

    f32x16 acc[4];
    #pragma unroll
    for (int t = 0; t < 4; ++t)
        #pragma unroll
        for (int r = 0; r < 16; ++r) acc[t][r] = 0.f;

    auto STAGE = [&](int buf, int kt) {
        #pragma unroll
        for (int i = 0; i < 4; ++i) {
            const int q = ((i & 1) << 8) | tid;
            const int row = q & 127, c = q >> 7;
            ushort* dst = smem + buf*8192 + ((i >> 1) << 12) + q*8;
            if (i < 2) {
                int t = row >> 5, r32 = row & 31;
                if (bm0 + r32 < BN_)
                    gload16(oh + ((size_t)(t*BN_ + bm0 + r32)*D_ + kt + c*8), dst);
            } else {
                gload16(wph + ((size_t)(bn0 + row)*D_ + kt + c*8), dst);
            }
        }
    };
    auto COMPUTE = [&](int buf) {
        const ushort* base = smem + buf*8192;
        #pragma unroll
        for (int s = 0; s < 2; ++s) {
            const int cA = (s << 1) | lg;
            f16x8 bv = *(const f16x8*)&base[4096 + (cA*128 + wn*32 + l31)*8];
            #pragma unroll
            for (int t = 0; t < 4; ++t) {
                f16x8 av = *(const f16x8*)&base[(cA*128 + t*32 + l31)*8];
                acc[t] = __builtin_amdgcn_mfma_f32_32x32x16_f16(av, bv, acc[t], 0, 0, 0);
            }
        }
    };

    STAGE(0, 0);
    __syncthreads();
    int cur = 0;
    #pragma unroll
    for (int k32 = 0; k32 < 16; ++k32) {
        if (k32 < 15) STAGE(cur ^ 1, (k32 + 1)*32);
        COMPUTE(cur);
        __syncthreads();
        cur ^= 1;
    }

    const int gcol = bn0 + wn*32 + l31;
    const float bb = bias[gcol];
    u32* fl = (u32*)smem;          // [wn][r][lg] flag halves
    #pragma unroll
    for (int r = 0; r < 16; ++r) {
        const int row32 = (r & 3) + 8*(r >> 2) + 4*lg;
        const bool live = bm0 + row32 < BN_;
        bool fg = false; float v = 0.f;
        #pragma unroll
        for (int t = 0; t < 4; ++t) {
            float h = v + ((acc[t][r] + bb) - v)*0.5f;
            bool st = h >= 1.0f;
            fg |= fabsf(h - 1.0f) < FLAG_TOL;
            if (live)
                outp[(size_t)t*PLANE + (size_t)(bm0 + row32)*D_ + gcol] = st ? 1.0f : 0.0f;
            v = st ? 0.f : h;
        }
        u64 fm = __ballot(fg);
        if (lane == 0) {
            fl[(wn*16 + r)*2 + 0] = (u32)fm;
            fl[(wn*16 + r)*2 + 1] = (u32)(fm >> 32);
        }
    }
    __syncthreads();
    if (tid < 64) {
        int rowf = tid >> 1, hlf = tid & 1;
        int rf = (rowf & 3) | ((rowf >> 3) << 2);
        int lgf = (rowf >> 2) & 1;
        u64 fw = (u64)fl[((2*hlf)*16 + rf)*2 + lgf]
               | ((u64)fl[((2*hlf+1)*16 + rf)*2 + lgf] << 32);
        if (bm0 + rowf < BN_)
            fmapp[(size_t)(bm0 + rowf)*8 + (bn0 >> 6) + hlf] = fw;
    }
}

// ---------------------------------------------------------------------------
// f64 exact recompute of flagged chains (bitmap scan, 4 waves/block, ILP).
// ---------------------------------------------------------------------------
__global__ __launch_bounds__(256)
void fixup_qkv(const float* __restrict__ x,
               const float* __restrict__ Wq, const float* __restrict__ Wk,
               const float* __restrict__ Wv,
               u64* __restrict__ bits3, const u64* __restrict__ flagmap)
{
    const int lane = threadIdx.x & 63;
    const int wv = blockIdx.x*4 + (threadIdx.x >> 6);
    const int nw = gridDim.x*4;
    for (int w = wv; w < NFW3; w += nw) {
        u64 fm = flagmap[w];
        while (fm) {
            int bit = __ffsll((long long)fm) - 1;
            fm &= fm - 1;
            int id = (w << 6) + bit;
            int tsr = id / PLANE;
            int rem = id - tsr*PLANE;
            int r = rem >> 9, e = rem & (D_-1);
            const float* W = (tsr==0) ? Wq : (tsr==1 ? Wk : Wv);
            const float* wr = W + (size_t)e*D_;
            u64* bits = bits3 + (size_t)tsr*MH;
            float wv8[8];
            #pragma unroll
            for (int i = 0; i < 8; ++i) wv8[i] = wr[lane + 64*i];
            double dots[T_];
            #pragma unroll
            for (int t = 0; t < T_; ++t) {
                const float* xr = x + (size_t)(t*BN_ + r)*D_;
                float xv8[8];
                #pragma unroll
                for (int i = 0; i < 8; ++i) xv8[i] = xr[lane + 64*i];
                double p = 0.0;
                #pragma unroll
                for (int i = 0; i < 8; ++i) p += (double)xv8[i]*(double)wv8[i];
                dots[t] = p;
            }
            #pragma unroll
            for (int off = 32; off > 0; off >>= 1)
                #pragma unroll
                for (int t = 0; t < T_; ++t)
                    dots[t] += __shfl_down(dots[t], off);
            if (lane == 0) {
                double v = 0.0;
                u64 b = 1ull << (e & 63);
                #pragma unroll
                for (int t = 0; t < T_; ++t) {
                    double hh = v + (dots[t] - v)/2.0;
                    bool s = hh >= 1.0;
                    size_t wd = (size_t)(t*BN_ + r)*H_ + (e >> 6);
                    if (s) atomicOr(&bits[wd], b);
                    else   atomicAnd(&bits[wd], ~b);
                    v = s ? 0.0 : hh;
                }
            }
        }
    }
}

// ---------------------------------------------------------------------------
// Fused MFMA attention. Q/K fragments unpacked from spike bit-words; QK^T ->
// bf16 S strip in per-wave LDS (exact); attn_map written with coalesced
// stride-1 row stores; PV against Vt -> of16.
// ---------------------------------------------------------------------------
#define JP 224   // 7 * 32 (padded j for PV K-dim)
#define VSTR 232 // LDS row stride for Vt / Ss

__global__ __launch_bounds__(256)
void attn_fused(const u64* __restrict__ qbits, const u64* __restrict__ kbits,
                const u64* __restrict__ vbits,
                float* __restrict__ attn_out, ushort* __restrict__ of16)
{
    __shared__ ushort Vt[DH][VSTR];
    __shared__ ushort Ss[4][16][VSTR];
    int tb = blockIdx.x, h = blockIdx.y;
    int tid = threadIdx.x, wave = tid >> 6, lane = tid & 63;

    // stage V transposed from vbits: Vt[d][j], j >= N_ zeroed
    for (int idx = tid; idx < JP*16; idx += 256) {
        int j = idx >> 4, d4 = (idx & 15) << 2;
        ushort vv[4] = {0,0,0,0};
        if (j < N_) {
            u64 vw = vbits[((size_t)tb*N_ + j)*H_ + h];
            #pragma unroll
            for (int r = 0; r < 4; ++r)
                vv[r] = ((vw >> (d4+r)) & 1ull) ? 0x3F80 : 0;
        }
        Vt[d4+0][j]=vv[0]; Vt[d4+1][j]=vv[1]; Vt[d4+2][j]=vv[2]; Vt[d4+3][j]=vv[3];
    }
    // zero Ss pad cols [208, 224)
    for (int idx = lane; idx < 16*16; idx += 64)
        Ss[wave][idx >> 4][208 + (idx & 15)] = 0;
    __syncthreads();

    const int il = lane & 15, kk = (lane >> 4) << 3, ig = (lane >> 4) << 2;
    const size_t amap = ((size_t)tb*H_ + h)*(size_t)(N_*N_);

    for (int it = wave; it < 13; it += 4) {
        int i0 = it << 4;
        // A-fragments straight from qbits
        int qrow = i0 + il;
        u64 qw = (qrow < N_) ? qbits[((size_t)tb*N_ + qrow)*H_ + h] : 0ull;
        short8v a0 = unpack8((u32)(qw >> kk));
        short8v a1 = unpack8((u32)((qw >> 32) >> kk));
        // QK^T over 13 col-tiles -> bf16 S strip (exact)
        for (int jt = 0; jt < 13; ++jt) {
            int j0 = jt << 4, jrow = j0 + il;
            u64 kw = (jrow < N_) ? kbits[((size_t)tb*N_ + jrow)*H_ + h] : 0ull;
            short8v b0 = unpack8((u32)(kw >> kk));
            short8v b1 = unpack8((u32)((kw >> 32) >> kk));
            f32x4 c = {0.f, 0.f, 0.f, 0.f};
            c = __builtin_amdgcn_mfma_f32_16x16x32_bf16(a0, b0, c, 0, 0, 0);
            c = __builtin_amdgcn_mfma_f32_16x16x32_bf16(a1, b1, c, 0, 0, 0);
            int j = j0 + il;               // C col = lane&15
            #pragma unroll
            for (int r = 0; r < 4; ++r) {
                float sv = c[r]*0.125f;    // exact: k/8, k <= 64
                Ss[wave][ig + r][j] = (ushort)(__float_as_uint(sv) >> 16);
            }
        }
        // coalesced attn_map row stores (bf16 -> f32 shift, exact)
        #pragma unroll
        for (int r = 0; r < 16; ++r) {
            int i = i0 + r;
            if (i < N_) {
                #pragma unroll
                for (int g = 0; g < 4; ++g) {
                    int col = g*64 + lane;
                    if (col < N_)
                        attn_out[amap + (size_t)i*N_ + col] =
                            __uint_as_float((u32)Ss[wave][r][col] << 16);
                }
            }
        }
        // PV for this strip
        f32x4 o[4];
        #pragma unroll
        for (int dt = 0; dt < 4; ++dt) o[dt] = (f32x4){0.f,0.f,0.f,0.f};
        #pragma unroll
        for (int kt = 0; kt < 7; ++kt) {
            short8v a = *(const short8v*)&Ss[wave][il][kt*32 + kk];
            #pragma unroll
            for (int dt = 0; dt < 4; ++dt) {
                short8v b = *(const short8v*)&Vt[dt*16 + il][kt*32 + kk];
                o[dt] = __builtin_amdgcn_mfma_f32_16x16x32_bf16(a, b, o[dt], 0, 0, 0);
            }
        }
        #pragma unroll
        for (int dt = 0; dt < 4; ++dt)
            #pragma unroll
            for (int r = 0; r < 4; ++r) {
                int i = i0 + ig + r;
                if (i < N_)
                    of16[((size_t)tb*N_ + i)*D_ + (size_t)h*DH + dt*16 + il] =
                        f16_bits(o[dt][r]);
            }
    }
}

// ---------------------------------------------------------------------------
// fixup_proj: exact f64 recompute of flagged proj chains (reads of16, exact).
// ---------------------------------------------------------------------------
__global__ __launch_bounds__(256)
void fixup_proj(const ushort* __restrict__ of16, const float* __restrict__ Wp,
                const float* __restrict__ bp, float* __restrict__ outp,
                const u64* __restrict__ flagmap)
{
    const int lane = threadIdx.x & 63;
    const int wv = blockIdx.x*4 + (threadIdx.x >> 6);
    const int nw = gridDim.x*4;
    for (int w = wv; w < NFWP; w += nw) {
        u64 fm = flagmap[w];
        while (fm) {
            int bit = __ffsll((long long)fm) - 1;
            fm &= fm - 1;
            int rem = (w << 6) + bit;
            int r = rem >> 9, e = rem & (D_-1);
            const float* wr = Wp + (size_t)e*D_;
            float wv8[8];
            #pragma unroll
            for (int i = 0; i < 8; ++i) wv8[i] = wr[lane + 64*i];
            double dots[T_];
            #pragma unroll
            for (int t = 0; t < T_; ++t) {
                const ushort* ar = of16 + (size_t)(t*BN_ + r)*D_;
                float av8[8];
                #pragma unroll
                for (int i = 0; i < 8; ++i) av8[i] = f16_val(ar[lane + 64*i]);
                double p = 0.0;
                #pragma unroll
                for (int i = 0; i < 8; ++i) p += (double)av8[i]*(double)wv8[i];
                dots[t] = p;
            }
            #pragma unroll
            for (int off = 32; off > 0; off >>= 1)
                #pragma unroll
                for (int t = 0; t < T_; ++t)
                    dots[t] += __shfl_down(dots[t], off);
            if (lane == 0) {
                double v = 0.0;
                #pragma unroll
                for (int t = 0; t < T_; ++t) {
                    double xt = dots[t] + (double)bp[e];
                    double h = v + (xt - v)/2.0;
                    bool s = h >= 1.0;
                    outp[(size_t)t*PLANE + rem] = s ? 1.0f : 0.0f;
                    v = s ? 0.0 : h;
                }
            }
        }
    }
}

// ---------------------------------------------------------------------------
extern "C" void kernel_launch(void* const* d_in, const int* in_sizes, int n_in,
                              void* d_out, int out_size, void* d_ws, size_t ws_size,
                              hipStream_t stream)
{
    const float* x  = (const float*)d_in[0];
    const float* Wq = (const float*)d_in[1];
    const float* Wk = (const float*)d_in[2];
    const float* Wv = (const float*)d_in[3];
    const float* Wp = (const float*)d_in[4];
    const float* bp = (const float*)d_in[5];
    float* out_spk  = (float*)d_out;                       // (T,B,N,D) spikes
    float* attn_out = (float*)d_out + TENSOR_ELEMS;        // (T,B,H,N,N)

    char* ws = (char*)d_ws;
    const size_t BUFB = (size_t)TENSOR_ELEMS * sizeof(float);   // 25.8 MB
    if (ws_size < 4*BUFB) return;
    // R2: O f16 (proj GEMM + fixup operand; exact)
    ushort* of16 = (ushort*)(ws + 2*BUFB);
    // R3: xh f16 | w3h | wph | bits | flag bitmaps
    char* r3 = ws + 3*BUFB;
    ushort* xh   = (ushort*)r3;                            // 12.9 MB
    ushort* w3h  = (ushort*)(r3 + (13u<<20));              // 1.5 MB
    ushort* wph  = (ushort*)(r3 + (15u<<20));              // 0.5 MB
    u64*    bits3 = (u64*)(r3 + (16u<<20));                // 2.42 MB
    u64*    qbits = bits3;
    u64*    kbits = bits3 + MH;
    u64*    vbits = bits3 + 2*(size_t)MH;
    u64*    fmap3 = (u64*)(r3 + (19u<<20));                // 605 KB
    u64*    fmapp = (u64*)(r3 + (20u<<20));                // 202 KB

    // f32 -> f16 conversions (single batched launch)
    cvt_all<<<NBX + 4*NBW, 256, 0, stream>>>(x, Wq, Wk, Wv, Wp, xh, w3h, wph);

    // QKV projections fused with LIF + bit-pack: grid 99 x (4 col x 3 w)
    gemm_qkv_lif<<<99*12, 256, 0, stream>>>(xh, w3h, bits3, fmap3);
    // exact f64 fixup of flagged chains (corrects single spike bits)
    fixup_qkv<<<2048, 256, 0, stream>>>(x, Wq, Wk, Wv, bits3, fmap3);

    // fused attention: QK^T -> attn_map + PV -> of16 (exact integer math)
    attn_fused<<<dim3(T_*B_, H_), 256, 0, stream>>>(
        qbits, kbits, vbits, attn_out, of16);

    // output projection fused with bias + LIF -> out_spk + flag bitmap
    gemm_proj_lif<<<99*4, 256, 0, stream>>>(of16, wph, bp, out_spk, fmapp);
    fixup_proj<<<1024, 256, 0, stream>>>(of16, Wp, bp, out_spk, fmapp);
}